// Round 6
// baseline (844.284 us; speedup 1.0000x reference)
//
#include <hip/hip_runtime.h>
#include <math.h>

#define N_ROWS 32768
#define K_CODES 8192
#define D_DIM 256
#define GUARD_STEPS 4u

typedef unsigned short u16;
typedef unsigned int u32;
typedef float f32x4 __attribute__((ext_vector_type(4)));
typedef short short8 __attribute__((ext_vector_type(8)));

#define GL_LDS(g, l) __builtin_amdgcn_global_load_lds( \
    (const __attribute__((address_space(1))) void*)(g), \
    (__attribute__((address_space(3))) void*)(l), 16, 0, 0)

// ---------------- bf16 split: x = hi + lo (both RNE bf16) ----------------
__device__ __forceinline__ void bf16_split(float x, u16& h, u16& l) {
    unsigned u = __float_as_uint(x);
    unsigned r = (u + 0x7fffu + ((u >> 16) & 1u)) >> 16;
    h = (u16)r;
    float hf = __uint_as_float(r << 16);
    float res = x - hf;               // exact (Sterbenz)
    unsigned u2 = __float_as_uint(res);
    unsigned r2 = (u2 + 0x7fffu + ((u2 >> 16) & 1u)) >> 16;
    l = (u16)r2;
}

// ---------------- fused split + row norm: one wave per row ----------------
__global__ void split_norm_kernel(const float* __restrict__ x, u16* __restrict__ hi,
                                  u16* __restrict__ lo, float* __restrict__ nrm, int nrows) {
    int gid = blockIdx.x * blockDim.x + threadIdx.x;
    int row = gid >> 6;
    int lane = gid & 63;
    if (row >= nrows) return;
    float4 v = ((const float4*)(x + (size_t)row * D_DIM))[lane];
    ushort4 h, l;
    bf16_split(v.x, h.x, l.x);
    bf16_split(v.y, h.y, l.y);
    bf16_split(v.z, h.z, l.z);
    bf16_split(v.w, h.w, l.w);
    ((ushort4*)(hi + (size_t)row * D_DIM))[lane] = h;
    ((ushort4*)(lo + (size_t)row * D_DIM))[lane] = l;
    double s = (double)v.x * v.x + (double)v.y * v.y + (double)v.z * v.z + (double)v.w * v.w;
    #pragma unroll
    for (int off = 32; off; off >>= 1) s += __shfl_xor(s, off);
    if (lane == 0) nrm[row] = (float)s;
}

// legacy norms (fallback path)
__global__ void row_norms_kernel(const float* __restrict__ x, float* __restrict__ nrm, int nrows) {
    int gid = blockIdx.x * blockDim.x + threadIdx.x;
    int row = gid >> 6;
    int lane = gid & 63;
    if (row >= nrows) return;
    float4 v = ((const float4*)(x + (size_t)row * D_DIM))[lane];
    double s = (double)v.x * v.x + (double)v.y * v.y + (double)v.z * v.z + (double)v.w * v.w;
    #pragma unroll
    for (int off = 32; off; off >>= 1) s += __shfl_xor(s, off);
    if (lane == 0) nrm[row] = (float)s;
}

// ---------------- pass A: 64-row tiles, 2 blocks/CU, 3-product MFMA argmin ----------------
// 256 threads = 4 waves (wn 0..3, wave tile 64 rows x 64 codes); K=64 chunks,
// serial stage->drain->compute per chunk; overlap comes from the co-resident partner block.
// LDS layout per tile: [kseg(8)][rows] of short8 (16-lane reads contiguous, conflict-free).
__global__ __launch_bounds__(256, 2) void mfma_pass_kernel(
    const u16* __restrict__ z1, const u16* __restrict__ z2,
    const u16* __restrict__ c1, const u16* __restrict__ c2,
    const float* __restrict__ rowN,
    int* __restrict__ idx_i, float* __restrict__ idx_f, int* __restrict__ cand2,
    int* __restrict__ flag_list, int* __restrict__ flag_count)
{
    __shared__ __align__(16) u16 z1s[8 * 64 * 8];    // 8 KB
    __shared__ __align__(16) u16 z2s[8 * 64 * 8];    // 8 KB
    __shared__ __align__(16) u16 c1s[8 * 256 * 8];   // 32 KB
    __shared__ __align__(16) u16 c2s[8 * 256 * 8];   // 32 KB  -> 80 KB total (2 blocks/CU)

    const int tid = threadIdx.x;
    const int lane = tid & 63;
    const int wn = tid >> 6;
    const int l15 = lane & 15, l4 = lane >> 4;
    const int row0 = blockIdx.x * 64;

    // row constants: rn (f32) and packed-key base bits
    float rnv[16];
    u32 rnb[16];
    #pragma unroll
    for (int fm = 0; fm < 4; ++fm)
        #pragma unroll
        for (int r = 0; r < 4; ++r) {
            float rv = rowN[row0 + fm * 16 + l4 * 4 + r];
            rnv[fm * 4 + r] = rv;
            rnb[fm * 4 + r] = __float_as_uint(rv) - 1024u;
        }

    u32 b1k[16], b2k[16];
    #pragma unroll
    for (int k = 0; k < 16; ++k) { b1k[k] = 0xFFFFFFFFu; b2k[k] = 0xFFFFFFFFu; }

    f32x4 acc[4][4];
    #pragma unroll
    for (int fm = 0; fm < 4; ++fm)
        #pragma unroll
        for (int fn = 0; fn < 4; ++fn) acc[fm][fn] = (f32x4){0.f, 0.f, 0.f, 0.f};

    for (int ct = 0; ct < 32; ++ct) {
        const int cbase = ct * 256;
        for (int kc = 0; kc < 4; ++kc) {
            const int ko = kc * 64;
            __syncthreads();
            // stage z1, z2 chunks [8 seg][64 rows]: 512 slots each, 2 loads/thread
            #pragma unroll
            for (int r = 0; r < 2; ++r) {
                int s = tid + 256 * r;
                int seg = s >> 6, rw = s & 63;
                GL_LDS(z1 + (size_t)(row0 + rw) * D_DIM + ko + seg * 8, z1s + s * 8);
            }
            #pragma unroll
            for (int r = 0; r < 2; ++r) {
                int s = tid + 256 * r;
                int seg = s >> 6, rw = s & 63;
                GL_LDS(z2 + (size_t)(row0 + rw) * D_DIM + ko + seg * 8, z2s + s * 8);
            }
            // stage c1, c2 chunks [8 seg][256 codes]: 2048 slots each, 8 loads/thread
            #pragma unroll
            for (int r = 0; r < 8; ++r) {
                int s = tid + 256 * r;
                int seg = s >> 8, cr = s & 255;
                GL_LDS(c1 + (size_t)(cbase + cr) * D_DIM + ko + seg * 8, c1s + s * 8);
            }
            #pragma unroll
            for (int r = 0; r < 8; ++r) {
                int s = tid + 256 * r;
                int seg = s >> 8, cr = s & 255;
                GL_LDS(c2 + (size_t)(cbase + cr) * D_DIM + ko + seg * 8, c2s + s * 8);
            }
            __syncthreads();

            #pragma unroll
            for (int kk = 0; kk < 2; ++kk) {
                const int seg = kk * 4 + l4;
                short8 a1[4], a2[4], b1f[4], b2f[4];
                #pragma unroll
                for (int fm = 0; fm < 4; ++fm) {
                    int rw = fm * 16 + l15;
                    a1[fm] = *(const short8*)(z1s + (seg * 64 + rw) * 8);
                    a2[fm] = *(const short8*)(z2s + (seg * 64 + rw) * 8);
                }
                #pragma unroll
                for (int fn = 0; fn < 4; ++fn) {
                    int cr = wn * 64 + fn * 16 + l15;
                    b1f[fn] = *(const short8*)(c1s + (seg * 256 + cr) * 8);
                    b2f[fn] = *(const short8*)(c2s + (seg * 256 + cr) * 8);
                }
                #pragma unroll
                for (int fm = 0; fm < 4; ++fm)
                    #pragma unroll
                    for (int fn = 0; fn < 4; ++fn) {
                        acc[fm][fn] = __builtin_amdgcn_mfma_f32_16x16x32_bf16(a1[fm], b1f[fn], acc[fm][fn], 0, 0, 0);
                        acc[fm][fn] = __builtin_amdgcn_mfma_f32_16x16x32_bf16(a2[fm], b1f[fn], acc[fm][fn], 0, 0, 0);
                        acc[fm][fn] = __builtin_amdgcn_mfma_f32_16x16x32_bf16(a1[fm], b2f[fn], acc[fm][fn], 0, 0, 0);
                    }
            }
        }
        // per-ct epilogue: dist = fl(rn - 2*dot); packed-u32 top-2; reset acc
        #pragma unroll
        for (int fn = 0; fn < 4; ++fn) {
            u32 code = (u32)(cbase + wn * 64 + fn * 16 + l15);
            #pragma unroll
            for (int fm = 0; fm < 4; ++fm)
                #pragma unroll
                for (int r2 = 0; r2 < 4; ++r2) {
                    int k16 = fm * 4 + r2;
                    float dist = fmaf(-2.0f, acc[fm][fn][r2], rnv[k16]);
                    u32 key = ((__float_as_uint(dist) - rnb[k16]) << 13) + code;
                    u32 t  = b1k[k16] > key ? b1k[k16] : key;
                    b1k[k16] = b1k[k16] < key ? b1k[k16] : key;
                    b2k[k16] = b2k[k16] < t ? b2k[k16] : t;
                    acc[fm][fn][r2] = 0.f;
                }
        }
    }

    // 16-lane merge (same rows across l15); packed keys carry lex tie-break
    #pragma unroll
    for (int off = 1; off < 16; off <<= 1) {
        #pragma unroll
        for (int k = 0; k < 16; ++k) {
            u32 o1 = (u32)__shfl_xor((int)b1k[k], off);
            u32 o2 = (u32)__shfl_xor((int)b2k[k], off);
            u32 mx = b1k[k] > o1 ? b1k[k] : o1;
            b1k[k] = b1k[k] < o1 ? b1k[k] : o1;
            u32 mn2 = b2k[k] < o2 ? b2k[k] : o2;
            b2k[k] = mn2 < mx ? mn2 : mx;
        }
    }
    // cross-wave (wn) merge: reuse z1s/z2s as u32 [4][64]
    __syncthreads();
    u32* mk1 = (u32*)z1s;
    u32* mk2 = (u32*)z2s;
    if (l15 == 0) {
        #pragma unroll
        for (int fm = 0; fm < 4; ++fm)
            #pragma unroll
            for (int r2 = 0; r2 < 4; ++r2) {
                int rl = fm * 16 + l4 * 4 + r2;
                mk1[wn * 64 + rl] = b1k[fm * 4 + r2];
                mk2[wn * 64 + rl] = b2k[fm * 4 + r2];
            }
    }
    __syncthreads();
    if (tid < 64) {
        u32 B1 = 0xFFFFFFFFu, B2 = 0xFFFFFFFFu;
        #pragma unroll
        for (int s = 0; s < 4; ++s) {
            u32 o1 = mk1[s * 64 + tid];
            u32 o2 = mk2[s * 64 + tid];
            u32 mx = B1 > o1 ? B1 : o1;
            B1 = B1 < o1 ? B1 : o1;
            u32 mn2 = B2 < o2 ? B2 : o2;
            B2 = mn2 < mx ? mn2 : mx;
        }
        int row = row0 + tid;
        int i1 = (int)(B1 & 8191u);
        idx_i[row] = i1;
        idx_f[row] = (float)i1;
        cand2[row] = (int)(B2 & 8191u);
        if ((B2 >> 13) - (B1 >> 13) <= GUARD_STEPS) {
            int p = atomicAdd(flag_count, 1);
            flag_list[p] = row;
        }
    }
}

// ---------------- lite rescan: one wave per flagged row, exact f32 dots of top-2 ----------------
__global__ __launch_bounds__(256) void lite_rescan_kernel(
    const float* __restrict__ z, const float* __restrict__ cb,
    const float* __restrict__ rowN, const int* __restrict__ flag_list,
    const int* __restrict__ flag_count, const int* __restrict__ cand2,
    int* __restrict__ idx_i, float* __restrict__ idx_f)
{
    int nflag = *flag_count;
    int widx = blockIdx.x * 4 + (threadIdx.x >> 6);
    if (widx >= nflag) return;
    int lane = threadIdx.x & 63;
    int row = flag_list[widx];
    int i1 = idx_i[row];
    int i2 = cand2[row];
    float rn = rowN[row];
    float4 zv = *(const float4*)(z + (size_t)row * D_DIM + lane * 4);
    float4 c1v = *(const float4*)(cb + (size_t)i1 * D_DIM + lane * 4);
    float4 c2v = *(const float4*)(cb + (size_t)i2 * D_DIM + lane * 4);
    float s1 = zv.x * c1v.x;
    s1 = fmaf(zv.y, c1v.y, s1);
    s1 = fmaf(zv.z, c1v.z, s1);
    s1 = fmaf(zv.w, c1v.w, s1);
    float s2 = zv.x * c2v.x;
    s2 = fmaf(zv.y, c2v.y, s2);
    s2 = fmaf(zv.z, c2v.z, s2);
    s2 = fmaf(zv.w, c2v.w, s2);
    #pragma unroll
    for (int off = 32; off; off >>= 1) {
        s1 += __shfl_xor(s1, off);
        s2 += __shfl_xor(s2, off);
    }
    float d1 = fmaf(-2.0f, s1, rn);
    float d2 = fmaf(-2.0f, s2, rn);
    bool w2 = (d2 < d1) || (d2 == d1 && i2 < i1);
    int win = w2 ? i2 : i1;
    if (lane == 0) {
        idx_i[row] = win;
        idx_f[row] = (float)win;
    }
}

// ---------------- z_q epilogue: one wave per row ----------------
__global__ void finalize_kernel(const float* __restrict__ z, const float* __restrict__ cb,
                                const float* __restrict__ noise, const int* __restrict__ idx,
                                float* __restrict__ zq)
{
    int gid = blockIdx.x * blockDim.x + threadIdx.x;
    int row = gid >> 6;
    int lane = gid & 63;
    if (row >= N_ROWS) return;
    const float4* zr = (const float4*)(z + (size_t)row * D_DIM);
    const float4* nr = (const float4*)(noise + (size_t)row * D_DIM);
    int k = idx[row];
    const float4* cr = (const float4*)(cb + (size_t)k * D_DIM);
    float4 zv = zr[lane], nv = nr[lane], cv = cr[lane];
    float4 dir, rv;
    dir.x = cv.x - zv.x; dir.y = cv.y - zv.y; dir.z = cv.z - zv.z; dir.w = cv.w - zv.w;
    rv.x = nv.x * 0.001f + dir.x; rv.y = nv.y * 0.001f + dir.y;
    rv.z = nv.z * 0.001f + dir.z; rv.w = nv.w * 0.001f + dir.w;
    float s_d = dir.x*dir.x + dir.y*dir.y + dir.z*dir.z + dir.w*dir.w;
    float s_r = rv.x*rv.x + rv.y*rv.y + rv.z*rv.z + rv.w*rv.w;
    #pragma unroll
    for (int off = 32; off; off >>= 1) {
        s_d += __shfl_xor(s_d, off);
        s_r += __shfl_xor(s_r, off);
    }
    float mag = sqrtf(s_d);
    float nrm = sqrtf(s_r);
    float scale = mag / fmaxf(nrm, 1e-12f);
    float4 o;
    o.x = zv.x + rv.x * scale; o.y = zv.y + rv.y * scale;
    o.z = zv.z + rv.z * scale; o.w = zv.w + rv.w * scale;
    ((float4*)(zq + (size_t)row * D_DIM))[lane] = o;
}

// ---------------- perplexity ----------------
__global__ void zero_kernel(int* __restrict__ h, int* __restrict__ cnt) {
    int i = blockIdx.x * 256 + threadIdx.x;
    if (i < K_CODES) h[i] = 0;
    if (i == K_CODES) *cnt = 0;
}
__global__ void hist_kernel(const int* __restrict__ idx, int* __restrict__ h) {
    int i = blockIdx.x * blockDim.x + threadIdx.x;
    if (i < N_ROWS) atomicAdd(&h[idx[i]], 1);
}
__global__ void perplexity_kernel(const int* __restrict__ h, float* __restrict__ out) {
    __shared__ double red[256];
    int tid = threadIdx.x;
    double s = 0.0;
    for (int j = tid; j < K_CODES; j += 256) {
        float p = (float)h[j] / 32768.0f;
        float t = p * logf(p + 1e-10f);
        s += (double)t;
    }
    red[tid] = s;
    __syncthreads();
    for (int off = 128; off; off >>= 1) {
        if (tid < off) red[tid] += red[tid + off];
        __syncthreads();
    }
    if (tid == 0) out[0] = (float)exp(-red[0]);
}

// ================= fallback f32 path (round-1, known-good) =================
#define BM 64
#define BN 128
#define BD 32
#define TM 4
#define TN 8
__global__ __launch_bounds__(256) void argmin_kernel(
    const float* __restrict__ z, const float* __restrict__ cb,
    const float* __restrict__ rowN, const float* __restrict__ codeN,
    int* __restrict__ idx_out, float* __restrict__ idx_f_out)
{
    __shared__ float As[BD][BM + 4];
    __shared__ float Bs[BD][BN + 4];
    const int tid = threadIdx.x;
    const int tx = tid & 15;
    const int ty = tid >> 4;
    const int row0 = blockIdx.x * BM;
    float rn[TM];
    #pragma unroll
    for (int tm = 0; tm < TM; ++tm) rn[tm] = rowN[row0 + ty * TM + tm];
    float bestVal[TM]; int bestIdx[TM];
    #pragma unroll
    for (int tm = 0; tm < TM; ++tm) { bestVal[tm] = INFINITY; bestIdx[tm] = 0; }
    for (int t0 = 0; t0 < K_CODES; t0 += BN) {
        float acc[TM][TN];
        #pragma unroll
        for (int tm = 0; tm < TM; ++tm)
            #pragma unroll
            for (int tn = 0; tn < TN; ++tn) acc[tm][tn] = 0.0f;
        for (int d0 = 0; d0 < D_DIM; d0 += BD) {
            __syncthreads();
            #pragma unroll
            for (int r = 0; r < 2; ++r) {
                int g = tid + 256 * r;
                int m = g >> 3, seg = g & 7;
                float4 v = *(const float4*)(z + (size_t)(row0 + m) * D_DIM + d0 + seg * 4);
                As[seg * 4 + 0][m] = v.x; As[seg * 4 + 1][m] = v.y;
                As[seg * 4 + 2][m] = v.z; As[seg * 4 + 3][m] = v.w;
            }
            #pragma unroll
            for (int r = 0; r < 4; ++r) {
                int g = tid + 256 * r;
                int c = g >> 3, seg = g & 7;
                float4 v = *(const float4*)(cb + (size_t)(t0 + c) * D_DIM + d0 + seg * 4);
                Bs[seg * 4 + 0][c] = v.x; Bs[seg * 4 + 1][c] = v.y;
                Bs[seg * 4 + 2][c] = v.z; Bs[seg * 4 + 3][c] = v.w;
            }
            __syncthreads();
            #pragma unroll
            for (int d = 0; d < BD; ++d) {
                float a[TM], b[TN];
                #pragma unroll
                for (int tm = 0; tm < TM; ++tm) a[tm] = As[d][ty * TM + tm];
                #pragma unroll
                for (int tn = 0; tn < TN; ++tn) b[tn] = Bs[d][tx * TN + tn];
                #pragma unroll
                for (int tm = 0; tm < TM; ++tm)
                    #pragma unroll
                    for (int tn = 0; tn < TN; ++tn)
                        acc[tm][tn] = fmaf(a[tm], b[tn], acc[tm][tn]);
            }
        }
        #pragma unroll
        for (int tn = 0; tn < TN; ++tn) {
            int code = t0 + tx * TN + tn;
            float cn = codeN[code];
            #pragma unroll
            for (int tm = 0; tm < TM; ++tm) {
                float c2 = 2.0f * acc[tm][tn];
                float ts = rn[tm] + cn;
                float dist = ts - c2;
                if (dist < bestVal[tm]) { bestVal[tm] = dist; bestIdx[tm] = code; }
            }
        }
    }
    #pragma unroll
    for (int off = 8; off; off >>= 1) {
        #pragma unroll
        for (int tm = 0; tm < TM; ++tm) {
            float ov = __shfl_xor(bestVal[tm], off, 16);
            int   oi = __shfl_xor(bestIdx[tm], off, 16);
            if (ov < bestVal[tm] || (ov == bestVal[tm] && oi < bestIdx[tm])) {
                bestVal[tm] = ov; bestIdx[tm] = oi;
            }
        }
    }
    if (tx == 0) {
        #pragma unroll
        for (int tm = 0; tm < TM; ++tm) {
            int row = row0 + ty * TM + tm;
            idx_out[row] = bestIdx[tm];
            idx_f_out[row] = (float)bestIdx[tm];
        }
    }
}

// =====================================================================
extern "C" void kernel_launch(void* const* d_in, const int* in_sizes, int n_in,
                              void* d_out, int out_size, void* d_ws, size_t ws_size,
                              hipStream_t stream)
{
    const float* z     = (const float*)d_in[0];
    const float* cb    = (const float*)d_in[1];
    const float* noise = (const float*)d_in[2];

    float* out   = (float*)d_out;
    float* zq    = out;
    float* idx_f = out + (size_t)N_ROWS * D_DIM;
    float* perp  = idx_f + N_ROWS;

    char* ws = (char*)d_ws;

    // workspace layout (bytes)
    const size_t OFF_Z1    = 0;
    const size_t OFF_Z2    = 16777216;
    const size_t OFF_C1    = 33554432;
    const size_t OFF_C2    = 37748736;
    const size_t OFF_ROWN  = 41943040;
    const size_t OFF_CODN  = 42074112;
    const size_t OFF_IDX   = 42106880;
    const size_t OFF_FLAGL = 42237952;
    const size_t OFF_FLAGC = 42369024;
    const size_t OFF_HIST  = 42369280;
    const size_t OFF_CAND2 = 42402048;
    const size_t NEED      = 42533120;

    if (ws_size >= NEED) {
        u16*   z1    = (u16*)(ws + OFF_Z1);
        u16*   z2    = (u16*)(ws + OFF_Z2);
        u16*   c1    = (u16*)(ws + OFF_C1);
        u16*   c2    = (u16*)(ws + OFF_C2);
        float* rowN  = (float*)(ws + OFF_ROWN);
        int*   idxi  = (int*)(ws + OFF_IDX);
        int*   flagl = (int*)(ws + OFF_FLAGL);
        int*   flagc = (int*)(ws + OFF_FLAGC);
        int*   hist  = (int*)(ws + OFF_HIST);
        int*   cand2 = (int*)(ws + OFF_CAND2);

        split_norm_kernel<<<N_ROWS / 4, 256, 0, stream>>>(z, z1, z2, rowN, N_ROWS);
        split_norm_kernel<<<K_CODES / 4, 256, 0, stream>>>(cb, c1, c2, (float*)(ws + OFF_CODN), K_CODES);
        zero_kernel<<<33, 256, 0, stream>>>(hist, flagc);
        mfma_pass_kernel<<<N_ROWS / 64, 256, 0, stream>>>(z1, z2, c1, c2, rowN,
                                                          idxi, idx_f, cand2, flagl, flagc);
        lite_rescan_kernel<<<N_ROWS / 4, 256, 0, stream>>>(z, cb, rowN, flagl, flagc,
                                                           cand2, idxi, idx_f);
        hist_kernel<<<N_ROWS / 256, 256, 0, stream>>>(idxi, hist);
        finalize_kernel<<<(N_ROWS * 64) / 256, 256, 0, stream>>>(z, cb, noise, idxi, zq);
        perplexity_kernel<<<1, 256, 0, stream>>>(hist, perp);
    } else {
        // fallback: round-1 pure-f32 path
        int*   idxi  = (int*)ws;
        int*   hist  = (int*)(ws + (size_t)N_ROWS * 4);
        float* rowN  = (float*)(ws + (size_t)(N_ROWS + K_CODES) * 4);
        float* codeN = (float*)(ws + (size_t)(2 * N_ROWS + K_CODES) * 4);
        int*   fc    = (int*)(ws + (size_t)(2 * N_ROWS + 2 * K_CODES) * 4);

        row_norms_kernel<<<N_ROWS / 4, 256, 0, stream>>>(z, rowN, N_ROWS);
        row_norms_kernel<<<K_CODES / 4, 256, 0, stream>>>(cb, codeN, K_CODES);
        argmin_kernel<<<N_ROWS / BM, 256, 0, stream>>>(z, cb, rowN, codeN, idxi, idx_f);
        zero_kernel<<<33, 256, 0, stream>>>(hist, fc);
        hist_kernel<<<N_ROWS / 256, 256, 0, stream>>>(idxi, hist);
        finalize_kernel<<<(N_ROWS * 64) / 256, 256, 0, stream>>>(z, cb, noise, idxi, zq);
        perplexity_kernel<<<1, 256, 0, stream>>>(hist, perp);
    }
}

// Round 7
// 791.725 us; speedup vs baseline: 1.0664x; 1.0664x over previous
//
#include <hip/hip_runtime.h>
#include <math.h>

#define N_ROWS 32768
#define K_CODES 8192
#define D_DIM 256
#define GUARD_STEPS 4u
#define NT 192   // 16 code-tiles * 12 K-tiles per block

typedef unsigned short u16;
typedef unsigned int u32;
typedef float f32x4 __attribute__((ext_vector_type(4)));
typedef short short8 __attribute__((ext_vector_type(8)));

#define GL_LDS(g, l) __builtin_amdgcn_global_load_lds( \
    (const __attribute__((address_space(1))) void*)(g), \
    (__attribute__((address_space(3))) void*)(l), 16, 0, 0)

// ---------------- bf16 split: x = hi + lo (both RNE bf16) ----------------
__device__ __forceinline__ void bf16_split(float x, u16& h, u16& l) {
    unsigned u = __float_as_uint(x);
    unsigned r = (u + 0x7fffu + ((u >> 16) & 1u)) >> 16;
    h = (u16)r;
    float hf = __uint_as_float(r << 16);
    float res = x - hf;               // exact (Sterbenz)
    unsigned u2 = __float_as_uint(res);
    unsigned r2 = (u2 + 0x7fffu + ((u2 >> 16) & 1u)) >> 16;
    l = (u16)r2;
}

// ---------------- fused split + row norm: one wave per row ----------------
__global__ void split_norm_kernel(const float* __restrict__ x, u16* __restrict__ hi,
                                  u16* __restrict__ lo, float* __restrict__ nrm, int nrows) {
    int gid = blockIdx.x * blockDim.x + threadIdx.x;
    int row = gid >> 6;
    int lane = gid & 63;
    if (row >= nrows) return;
    float4 v = ((const float4*)(x + (size_t)row * D_DIM))[lane];
    ushort4 h, l;
    bf16_split(v.x, h.x, l.x);
    bf16_split(v.y, h.y, l.y);
    bf16_split(v.z, h.z, l.z);
    bf16_split(v.w, h.w, l.w);
    ((ushort4*)(hi + (size_t)row * D_DIM))[lane] = h;
    ((ushort4*)(lo + (size_t)row * D_DIM))[lane] = l;
    double s = (double)v.x * v.x + (double)v.y * v.y + (double)v.z * v.z + (double)v.w * v.w;
    #pragma unroll
    for (int off = 32; off; off >>= 1) s += __shfl_xor(s, off);
    if (lane == 0) nrm[row] = (float)s;
}

// legacy norms (fallback path)
__global__ void row_norms_kernel(const float* __restrict__ x, float* __restrict__ nrm, int nrows) {
    int gid = blockIdx.x * blockDim.x + threadIdx.x;
    int row = gid >> 6;
    int lane = gid & 63;
    if (row >= nrows) return;
    float4 v = ((const float4*)(x + (size_t)row * D_DIM))[lane];
    double s = (double)v.x * v.x + (double)v.y * v.y + (double)v.z * v.z + (double)v.w * v.w;
    #pragma unroll
    for (int off = 32; off; off >>= 1) s += __shfl_xor(s, off);
    if (lane == 0) nrm[row] = (float)s;
}

// ---------------- pass A: 256x256 tile, 2-deep counted-vmcnt pipeline ----------------
// 512 threads = 8 waves (wm 0..3 x wn 0..1); wave tile 64 rows x 128 codes.
// Block covers 256 rows x 4096 codes (one code half). K-tile = 64 of one segment;
// segments per code-tile: z1*c1, z2*c1, z1*c2 (kc 0..3 each) -> 12 K-tiles/ct, 16 ct.
// LDS: A/B double-buffered [buf][8 seg][256] of short8 = 128 KB, conflict-free reads.
__global__ __launch_bounds__(512, 2) void mfma_pass_kernel(
    const u16* __restrict__ z1, const u16* __restrict__ z2,
    const u16* __restrict__ c1, const u16* __restrict__ c2,
    const float* __restrict__ rowN,
    u32* __restrict__ g1k, u32* __restrict__ g2k)
{
    __shared__ __align__(16) u16 As[2][2048 * 8];   // 64 KB
    __shared__ __align__(16) u16 Bs[2][2048 * 8];   // 64 KB

    const int tid = threadIdx.x;
    const int lane = tid & 63;
    const int w = tid >> 6;
    const int wm = w >> 1, wn = w & 1;
    const int l15 = lane & 15, l4 = lane >> 4;

    // bijective XCD-pinned decode: codes-half h lives on XCDs {4h..4h+3}
    const int wg = blockIdx.x;
    const int xcd = wg & 7;
    const int half = xcd >> 2;
    const int rowblk = (xcd & 3) * 32 + (wg >> 3);
    const int row0 = rowblk * 256;
    const int cb0 = half * 4096;

    // row constants (loaded first so they drain before tile0 in vmcnt order)
    float rnv[16];
    u32 rnb[16];
    #pragma unroll
    for (int fm = 0; fm < 4; ++fm)
        #pragma unroll
        for (int r = 0; r < 4; ++r) {
            float rv = rowN[row0 + wm * 64 + fm * 16 + l4 * 4 + r];
            rnv[fm * 4 + r] = rv;
            rnb[fm * 4 + r] = __float_as_uint(rv) - 1024u;
        }

    u32 b1k[16], b2k[16];
    #pragma unroll
    for (int k = 0; k < 16; ++k) { b1k[k] = 0xFFFFFFFFu; b2k[k] = 0xFFFFFFFFu; }

    f32x4 acc[4][8];
    #pragma unroll
    for (int fm = 0; fm < 4; ++fm)
        #pragma unroll
        for (int fn = 0; fn < 8; ++fn) acc[fm][fn] = (f32x4){0.f, 0.f, 0.f, 0.f};

    // stage one K-tile (A half 32 KB + B half 32 KB): 8 global_load_lds per thread
    auto stage_at = [&](int ct, int sub, int buf) {
        const int seg = sub >> 2, kc = sub & 3, ko = kc * 64;
        const u16* Ap = (seg == 1) ? z2 : z1;
        const u16* Bp = (seg == 2) ? c2 : c1;
        const int cbase = cb0 + ct * 256;
        #pragma unroll
        for (int r = 0; r < 4; ++r) {
            int s = tid + 512 * r;
            int arow = s & 255, aseg = s >> 8;
            GL_LDS(Ap + (size_t)(row0 + arow) * D_DIM + ko + aseg * 8, As[buf] + s * 8);
        }
        #pragma unroll
        for (int r = 0; r < 4; ++r) {
            int s = tid + 512 * r;
            int brow = s & 255, bseg = s >> 8;
            GL_LDS(Bp + (size_t)(cbase + brow) * D_DIM + ko + bseg * 8, Bs[buf] + s * 8);
        }
    };

    stage_at(0, 0, 0);
    stage_at(0, 1, 1);

    int s_ct = 0, s_sub = 2;   // tile being staged  (= t+2)
    int c_ct = 0, c_sub = 0;   // tile being computed (= t)

    for (int t = 0; t < NT; ++t) {
        const int buf = t & 1;
        if (t < NT - 1) { asm volatile("s_waitcnt vmcnt(8)" ::: "memory"); }
        else           { asm volatile("s_waitcnt vmcnt(0)" ::: "memory"); }
        __builtin_amdgcn_s_barrier();

        const u16* Ab = As[buf];
        const u16* Bb = Bs[buf];
        // kk = 0 (seg16 = l4)
        {
            short8 a[4], b[8];
            #pragma unroll
            for (int fm = 0; fm < 4; ++fm)
                a[fm] = *(const short8*)(Ab + (l4 * 256 + wm * 64 + fm * 16 + l15) * 8);
            #pragma unroll
            for (int fn = 0; fn < 8; ++fn)
                b[fn] = *(const short8*)(Bb + (l4 * 256 + wn * 128 + fn * 16 + l15) * 8);
            __builtin_amdgcn_s_setprio(1);
            #pragma unroll
            for (int fm = 0; fm < 4; ++fm)
                #pragma unroll
                for (int fn = 0; fn < 8; ++fn)
                    acc[fm][fn] = __builtin_amdgcn_mfma_f32_16x16x32_bf16(a[fm], b[fn], acc[fm][fn], 0, 0, 0);
            __builtin_amdgcn_s_setprio(0);
        }
        // kk = 1 (seg16 = 4 + l4)
        {
            short8 a[4], b[8];
            #pragma unroll
            for (int fm = 0; fm < 4; ++fm)
                a[fm] = *(const short8*)(Ab + ((4 + l4) * 256 + wm * 64 + fm * 16 + l15) * 8);
            #pragma unroll
            for (int fn = 0; fn < 8; ++fn)
                b[fn] = *(const short8*)(Bb + ((4 + l4) * 256 + wn * 128 + fn * 16 + l15) * 8);
            __builtin_amdgcn_s_setprio(1);
            #pragma unroll
            for (int fm = 0; fm < 4; ++fm)
                #pragma unroll
                for (int fn = 0; fn < 8; ++fn)
                    acc[fm][fn] = __builtin_amdgcn_mfma_f32_16x16x32_bf16(a[fm], b[fn], acc[fm][fn], 0, 0, 0);
            __builtin_amdgcn_s_setprio(0);
        }

        asm volatile("s_waitcnt lgkmcnt(0)" ::: "memory");
        __builtin_amdgcn_s_barrier();

        if (t + 2 < NT) stage_at(s_ct, s_sub, buf);   // overwrite just-read buffer

        if (c_sub == 11) {
            // per-code-tile epilogue: dist = fl(rn - 2*dot); packed-u32 top-2; reset acc
            #pragma unroll
            for (int fn = 0; fn < 8; ++fn) {
                u32 code = (u32)(cb0 + c_ct * 256 + wn * 128 + fn * 16 + l15);
                #pragma unroll
                for (int fm = 0; fm < 4; ++fm)
                    #pragma unroll
                    for (int r2 = 0; r2 < 4; ++r2) {
                        int k16 = fm * 4 + r2;
                        float dist = fmaf(-2.0f, acc[fm][fn][r2], rnv[k16]);
                        u32 key = ((__float_as_uint(dist) - rnb[k16]) << 13) + code;
                        u32 mx = b1k[k16] > key ? b1k[k16] : key;
                        b1k[k16] = b1k[k16] < key ? b1k[k16] : key;
                        b2k[k16] = b2k[k16] < mx ? b2k[k16] : mx;
                        acc[fm][fn][r2] = 0.f;
                    }
            }
        }
        if (++s_sub == 12) { s_sub = 0; ++s_ct; }
        if (++c_sub == 12) { c_sub = 0; ++c_ct; }
    }

    // 16-lane merge (same rows across l15); packed keys carry lex tie-break
    #pragma unroll
    for (int off = 1; off < 16; off <<= 1) {
        #pragma unroll
        for (int k = 0; k < 16; ++k) {
            u32 o1 = (u32)__shfl_xor((int)b1k[k], off);
            u32 o2 = (u32)__shfl_xor((int)b2k[k], off);
            u32 mx = b1k[k] > o1 ? b1k[k] : o1;
            b1k[k] = b1k[k] < o1 ? b1k[k] : o1;
            u32 mn2 = b2k[k] < o2 ? b2k[k] : o2;
            b2k[k] = mn2 < mx ? mn2 : mx;
        }
    }
    // cross-wave (wn) merge via reused LDS
    __syncthreads();
    u32* mk1 = (u32*)As;           // [2][256]
    u32* mk2 = mk1 + 512;
    if (l15 == 0) {
        #pragma unroll
        for (int fm = 0; fm < 4; ++fm)
            #pragma unroll
            for (int r2 = 0; r2 < 4; ++r2) {
                int rl = wm * 64 + fm * 16 + l4 * 4 + r2;
                mk1[wn * 256 + rl] = b1k[fm * 4 + r2];
                mk2[wn * 256 + rl] = b2k[fm * 4 + r2];
            }
    }
    __syncthreads();
    if (tid < 256) {
        u32 a1 = mk1[tid], b1 = mk1[256 + tid];
        u32 a2 = mk2[tid], b2 = mk2[256 + tid];
        u32 B1 = a1 < b1 ? a1 : b1;
        u32 mx = a1 > b1 ? a1 : b1;
        u32 mn2 = a2 < b2 ? a2 : b2;
        u32 B2 = mn2 < mx ? mn2 : mx;
        g1k[(size_t)half * N_ROWS + row0 + tid] = B1;
        g2k[(size_t)half * N_ROWS + row0 + tid] = B2;
    }
}

// ---------------- combine halves, write idx, flag ambiguous rows ----------------
__global__ void combine_kernel(const u32* __restrict__ g1k, const u32* __restrict__ g2k,
                               int* __restrict__ idx_i, float* __restrict__ idx_f,
                               int* __restrict__ cand2, int* __restrict__ flag_list,
                               int* __restrict__ flag_count)
{
    int row = blockIdx.x * 256 + threadIdx.x;
    u32 a1 = g1k[row], b1 = g1k[N_ROWS + row];
    u32 a2 = g2k[row], b2 = g2k[N_ROWS + row];
    u32 B1 = a1 < b1 ? a1 : b1;
    u32 mx = a1 > b1 ? a1 : b1;
    u32 mn2 = a2 < b2 ? a2 : b2;
    u32 B2 = mn2 < mx ? mn2 : mx;
    int i1 = (int)(B1 & 8191u);
    idx_i[row] = i1;
    idx_f[row] = (float)i1;
    cand2[row] = (int)(B2 & 8191u);
    if ((B2 >> 13) - (B1 >> 13) <= GUARD_STEPS) {
        int p = atomicAdd(flag_count, 1);
        flag_list[p] = row;
    }
}

// ---------------- lite rescan: one wave per flagged row, exact f32 dots of top-2 ----------------
__global__ __launch_bounds__(256) void lite_rescan_kernel(
    const float* __restrict__ z, const float* __restrict__ cb,
    const float* __restrict__ rowN, const int* __restrict__ flag_list,
    const int* __restrict__ flag_count, const int* __restrict__ cand2,
    int* __restrict__ idx_i, float* __restrict__ idx_f)
{
    int nflag = *flag_count;
    int widx = blockIdx.x * 4 + (threadIdx.x >> 6);
    if (widx >= nflag) return;
    int lane = threadIdx.x & 63;
    int row = flag_list[widx];
    int i1 = idx_i[row];
    int i2 = cand2[row];
    float rn = rowN[row];
    float4 zv = *(const float4*)(z + (size_t)row * D_DIM + lane * 4);
    float4 c1v = *(const float4*)(cb + (size_t)i1 * D_DIM + lane * 4);
    float4 c2v = *(const float4*)(cb + (size_t)i2 * D_DIM + lane * 4);
    float s1 = zv.x * c1v.x;
    s1 = fmaf(zv.y, c1v.y, s1);
    s1 = fmaf(zv.z, c1v.z, s1);
    s1 = fmaf(zv.w, c1v.w, s1);
    float s2 = zv.x * c2v.x;
    s2 = fmaf(zv.y, c2v.y, s2);
    s2 = fmaf(zv.z, c2v.z, s2);
    s2 = fmaf(zv.w, c2v.w, s2);
    #pragma unroll
    for (int off = 32; off; off >>= 1) {
        s1 += __shfl_xor(s1, off);
        s2 += __shfl_xor(s2, off);
    }
    float d1 = fmaf(-2.0f, s1, rn);
    float d2 = fmaf(-2.0f, s2, rn);
    bool w2 = (d2 < d1) || (d2 == d1 && i2 < i1);
    int win = w2 ? i2 : i1;
    if (lane == 0) {
        idx_i[row] = win;
        idx_f[row] = (float)win;
    }
}

// ---------------- z_q epilogue: one wave per row ----------------
__global__ void finalize_kernel(const float* __restrict__ z, const float* __restrict__ cb,
                                const float* __restrict__ noise, const int* __restrict__ idx,
                                float* __restrict__ zq)
{
    int gid = blockIdx.x * blockDim.x + threadIdx.x;
    int row = gid >> 6;
    int lane = gid & 63;
    if (row >= N_ROWS) return;
    const float4* zr = (const float4*)(z + (size_t)row * D_DIM);
    const float4* nr = (const float4*)(noise + (size_t)row * D_DIM);
    int k = idx[row];
    const float4* cr = (const float4*)(cb + (size_t)k * D_DIM);
    float4 zv = zr[lane], nv = nr[lane], cv = cr[lane];
    float4 dir, rv;
    dir.x = cv.x - zv.x; dir.y = cv.y - zv.y; dir.z = cv.z - zv.z; dir.w = cv.w - zv.w;
    rv.x = nv.x * 0.001f + dir.x; rv.y = nv.y * 0.001f + dir.y;
    rv.z = nv.z * 0.001f + dir.z; rv.w = nv.w * 0.001f + dir.w;
    float s_d = dir.x*dir.x + dir.y*dir.y + dir.z*dir.z + dir.w*dir.w;
    float s_r = rv.x*rv.x + rv.y*rv.y + rv.z*rv.z + rv.w*rv.w;
    #pragma unroll
    for (int off = 32; off; off >>= 1) {
        s_d += __shfl_xor(s_d, off);
        s_r += __shfl_xor(s_r, off);
    }
    float mag = sqrtf(s_d);
    float nrm = sqrtf(s_r);
    float scale = mag / fmaxf(nrm, 1e-12f);
    float4 o;
    o.x = zv.x + rv.x * scale; o.y = zv.y + rv.y * scale;
    o.z = zv.z + rv.z * scale; o.w = zv.w + rv.w * scale;
    ((float4*)(zq + (size_t)row * D_DIM))[lane] = o;
}

// ---------------- perplexity ----------------
__global__ void zero_kernel(int* __restrict__ h, int* __restrict__ cnt) {
    int i = blockIdx.x * 256 + threadIdx.x;
    if (i < K_CODES) h[i] = 0;
    if (i == K_CODES) *cnt = 0;
}
__global__ void hist_kernel(const int* __restrict__ idx, int* __restrict__ h) {
    int i = blockIdx.x * blockDim.x + threadIdx.x;
    if (i < N_ROWS) atomicAdd(&h[idx[i]], 1);
}
__global__ void perplexity_kernel(const int* __restrict__ h, float* __restrict__ out) {
    __shared__ double red[256];
    int tid = threadIdx.x;
    double s = 0.0;
    for (int j = tid; j < K_CODES; j += 256) {
        float p = (float)h[j] / 32768.0f;
        float t = p * logf(p + 1e-10f);
        s += (double)t;
    }
    red[tid] = s;
    __syncthreads();
    for (int off = 128; off; off >>= 1) {
        if (tid < off) red[tid] += red[tid + off];
        __syncthreads();
    }
    if (tid == 0) out[0] = (float)exp(-red[0]);
}

// ================= fallback f32 path (round-1, known-good) =================
#define BM 64
#define BN 128
#define BD 32
#define TM 4
#define TN 8
__global__ __launch_bounds__(256) void argmin_kernel(
    const float* __restrict__ z, const float* __restrict__ cb,
    const float* __restrict__ rowN, const float* __restrict__ codeN,
    int* __restrict__ idx_out, float* __restrict__ idx_f_out)
{
    __shared__ float As[BD][BM + 4];
    __shared__ float Bs[BD][BN + 4];
    const int tid = threadIdx.x;
    const int tx = tid & 15;
    const int ty = tid >> 4;
    const int row0 = blockIdx.x * BM;
    float rn[TM];
    #pragma unroll
    for (int tm = 0; tm < TM; ++tm) rn[tm] = rowN[row0 + ty * TM + tm];
    float bestVal[TM]; int bestIdx[TM];
    #pragma unroll
    for (int tm = 0; tm < TM; ++tm) { bestVal[tm] = INFINITY; bestIdx[tm] = 0; }
    for (int t0 = 0; t0 < K_CODES; t0 += BN) {
        float acc[TM][TN];
        #pragma unroll
        for (int tm = 0; tm < TM; ++tm)
            #pragma unroll
            for (int tn = 0; tn < TN; ++tn) acc[tm][tn] = 0.0f;
        for (int d0 = 0; d0 < D_DIM; d0 += BD) {
            __syncthreads();
            #pragma unroll
            for (int r = 0; r < 2; ++r) {
                int g = tid + 256 * r;
                int m = g >> 3, seg = g & 7;
                float4 v = *(const float4*)(z + (size_t)(row0 + m) * D_DIM + d0 + seg * 4);
                As[seg * 4 + 0][m] = v.x; As[seg * 4 + 1][m] = v.y;
                As[seg * 4 + 2][m] = v.z; As[seg * 4 + 3][m] = v.w;
            }
            #pragma unroll
            for (int r = 0; r < 4; ++r) {
                int g = tid + 256 * r;
                int c = g >> 3, seg = g & 7;
                float4 v = *(const float4*)(cb + (size_t)(t0 + c) * D_DIM + d0 + seg * 4);
                Bs[seg * 4 + 0][c] = v.x; Bs[seg * 4 + 1][c] = v.y;
                Bs[seg * 4 + 2][c] = v.z; Bs[seg * 4 + 3][c] = v.w;
            }
            __syncthreads();
            #pragma unroll
            for (int d = 0; d < BD; ++d) {
                float a[TM], b[TN];
                #pragma unroll
                for (int tm = 0; tm < TM; ++tm) a[tm] = As[d][ty * TM + tm];
                #pragma unroll
                for (int tn = 0; tn < TN; ++tn) b[tn] = Bs[d][tx * TN + tn];
                #pragma unroll
                for (int tm = 0; tm < TM; ++tm)
                    #pragma unroll
                    for (int tn = 0; tn < TN; ++tn)
                        acc[tm][tn] = fmaf(a[tm], b[tn], acc[tm][tn]);
            }
        }
        #pragma unroll
        for (int tn = 0; tn < TN; ++tn) {
            int code = t0 + tx * TN + tn;
            float cn = codeN[code];
            #pragma unroll
            for (int tm = 0; tm < TM; ++tm) {
                float c2 = 2.0f * acc[tm][tn];
                float ts = rn[tm] + cn;
                float dist = ts - c2;
                if (dist < bestVal[tm]) { bestVal[tm] = dist; bestIdx[tm] = code; }
            }
        }
    }
    #pragma unroll
    for (int off = 8; off; off >>= 1) {
        #pragma unroll
        for (int tm = 0; tm < TM; ++tm) {
            float ov = __shfl_xor(bestVal[tm], off, 16);
            int   oi = __shfl_xor(bestIdx[tm], off, 16);
            if (ov < bestVal[tm] || (ov == bestVal[tm] && oi < bestIdx[tm])) {
                bestVal[tm] = ov; bestIdx[tm] = oi;
            }
        }
    }
    if (tx == 0) {
        #pragma unroll
        for (int tm = 0; tm < TM; ++tm) {
            int row = row0 + ty * TM + tm;
            idx_out[row] = bestIdx[tm];
            idx_f_out[row] = (float)bestIdx[tm];
        }
    }
}

// =====================================================================
extern "C" void kernel_launch(void* const* d_in, const int* in_sizes, int n_in,
                              void* d_out, int out_size, void* d_ws, size_t ws_size,
                              hipStream_t stream)
{
    const float* z     = (const float*)d_in[0];
    const float* cb    = (const float*)d_in[1];
    const float* noise = (const float*)d_in[2];

    float* out   = (float*)d_out;
    float* zq    = out;
    float* idx_f = out + (size_t)N_ROWS * D_DIM;
    float* perp  = idx_f + N_ROWS;

    char* ws = (char*)d_ws;

    // workspace layout (bytes)
    const size_t OFF_Z1    = 0;
    const size_t OFF_Z2    = 16777216;
    const size_t OFF_C1    = 33554432;
    const size_t OFF_C2    = 37748736;
    const size_t OFF_ROWN  = 41943040;
    const size_t OFF_CODN  = 42074112;
    const size_t OFF_IDX   = 42106880;
    const size_t OFF_FLAGL = 42237952;
    const size_t OFF_FLAGC = 42369024;
    const size_t OFF_HIST  = 42369280;
    const size_t OFF_CAND2 = 42402048;
    const size_t OFF_G1K   = 42533120;
    const size_t OFF_G2K   = 42795264;
    const size_t NEED      = 43057408;

    if (ws_size >= NEED) {
        u16*   z1    = (u16*)(ws + OFF_Z1);
        u16*   z2    = (u16*)(ws + OFF_Z2);
        u16*   c1    = (u16*)(ws + OFF_C1);
        u16*   c2    = (u16*)(ws + OFF_C2);
        float* rowN  = (float*)(ws + OFF_ROWN);
        int*   idxi  = (int*)(ws + OFF_IDX);
        int*   flagl = (int*)(ws + OFF_FLAGL);
        int*   flagc = (int*)(ws + OFF_FLAGC);
        int*   hist  = (int*)(ws + OFF_HIST);
        int*   cand2 = (int*)(ws + OFF_CAND2);
        u32*   g1k   = (u32*)(ws + OFF_G1K);
        u32*   g2k   = (u32*)(ws + OFF_G2K);

        split_norm_kernel<<<N_ROWS / 4, 256, 0, stream>>>(z, z1, z2, rowN, N_ROWS);
        split_norm_kernel<<<K_CODES / 4, 256, 0, stream>>>(cb, c1, c2, (float*)(ws + OFF_CODN), K_CODES);
        zero_kernel<<<33, 256, 0, stream>>>(hist, flagc);
        mfma_pass_kernel<<<256, 512, 0, stream>>>(z1, z2, c1, c2, rowN, g1k, g2k);
        combine_kernel<<<N_ROWS / 256, 256, 0, stream>>>(g1k, g2k, idxi, idx_f, cand2,
                                                         flagl, flagc);
        lite_rescan_kernel<<<N_ROWS / 4, 256, 0, stream>>>(z, cb, rowN, flagl, flagc,
                                                           cand2, idxi, idx_f);
        hist_kernel<<<N_ROWS / 256, 256, 0, stream>>>(idxi, hist);
        finalize_kernel<<<(N_ROWS * 64) / 256, 256, 0, stream>>>(z, cb, noise, idxi, zq);
        perplexity_kernel<<<1, 256, 0, stream>>>(hist, perp);
    } else {
        // fallback: round-1 pure-f32 path
        int*   idxi  = (int*)ws;
        int*   hist  = (int*)(ws + (size_t)N_ROWS * 4);
        float* rowN  = (float*)(ws + (size_t)(N_ROWS + K_CODES) * 4);
        float* codeN = (float*)(ws + (size_t)(2 * N_ROWS + K_CODES) * 4);
        int*   fc    = (int*)(ws + (size_t)(2 * N_ROWS + 2 * K_CODES) * 4);

        row_norms_kernel<<<N_ROWS / 4, 256, 0, stream>>>(z, rowN, N_ROWS);
        row_norms_kernel<<<K_CODES / 4, 256, 0, stream>>>(cb, codeN, K_CODES);
        argmin_kernel<<<N_ROWS / BM, 256, 0, stream>>>(z, cb, rowN, codeN, idxi, idx_f);
        zero_kernel<<<33, 256, 0, stream>>>(hist, fc);
        hist_kernel<<<N_ROWS / 256, 256, 0, stream>>>(idxi, hist);
        finalize_kernel<<<(N_ROWS * 64) / 256, 256, 0, stream>>>(z, cb, noise, idxi, zq);
        perplexity_kernel<<<1, 256, 0, stream>>>(hist, perp);
    }
}

// Round 9
// 769.816 us; speedup vs baseline: 1.0967x; 1.0285x over previous
//
#include <hip/hip_runtime.h>
#include <math.h>

#define N_ROWS 32768
#define K_CODES 8192
#define D_DIM 256
#define GUARD_STEPS 4u
#define NTT 96   // 8 code-tiles * 12 segment-K-tiles per block

typedef unsigned short u16;
typedef unsigned int u32;
typedef float f32x4 __attribute__((ext_vector_type(4)));
typedef short short8 __attribute__((ext_vector_type(8)));

#define GL_LDS(g, l) __builtin_amdgcn_global_load_lds( \
    (const __attribute__((address_space(1))) void*)(g), \
    (__attribute__((address_space(3))) void*)(l), 16, 0, 0)

// ---------------- bf16 split: x = hi + lo (both RNE bf16) ----------------
__device__ __forceinline__ void bf16_split(float x, u16& h, u16& l) {
    unsigned u = __float_as_uint(x);
    unsigned r = (u + 0x7fffu + ((u >> 16) & 1u)) >> 16;
    h = (u16)r;
    float hf = __uint_as_float(r << 16);
    float res = x - hf;               // exact (Sterbenz)
    unsigned u2 = __float_as_uint(res);
    unsigned r2 = (u2 + 0x7fffu + ((u2 >> 16) & 1u)) >> 16;
    l = (u16)r2;
}

// ---------------- fused split + row norm: one wave per row ----------------
__global__ void split_norm_kernel(const float* __restrict__ x, u16* __restrict__ hi,
                                  u16* __restrict__ lo, float* __restrict__ nrm, int nrows) {
    int gid = blockIdx.x * blockDim.x + threadIdx.x;
    int row = gid >> 6;
    int lane = gid & 63;
    if (row >= nrows) return;
    float4 v = ((const float4*)(x + (size_t)row * D_DIM))[lane];
    ushort4 h, l;
    bf16_split(v.x, h.x, l.x);
    bf16_split(v.y, h.y, l.y);
    bf16_split(v.z, h.z, l.z);
    bf16_split(v.w, h.w, l.w);
    ((ushort4*)(hi + (size_t)row * D_DIM))[lane] = h;
    ((ushort4*)(lo + (size_t)row * D_DIM))[lane] = l;
    double s = (double)v.x * v.x + (double)v.y * v.y + (double)v.z * v.z + (double)v.w * v.w;
    #pragma unroll
    for (int off = 32; off; off >>= 1) s += __shfl_xor(s, off);
    if (lane == 0) nrm[row] = (float)s;
}

// legacy norms (fallback path)
__global__ void row_norms_kernel(const float* __restrict__ x, float* __restrict__ nrm, int nrows) {
    int gid = blockIdx.x * blockDim.x + threadIdx.x;
    int row = gid >> 6;
    int lane = gid & 63;
    if (row >= nrows) return;
    float4 v = ((const float4*)(x + (size_t)row * D_DIM))[lane];
    double s = (double)v.x * v.x + (double)v.y * v.y + (double)v.z * v.z + (double)v.w * v.w;
    #pragma unroll
    for (int off = 32; off; off >>= 1) s += __shfl_xor(s, off);
    if (lane == 0) nrm[row] = (float)s;
}

// ---------------- pass A: phased pipeline (vmcnt -> barrier -> stage/read -> MFMA) ----------------
// 512 blocks = 128 row-tiles(256 rows) x 4 code-slices(2048). 512 thr = 8 waves (wm 0..3 x wn 0..1),
// wave tile 64 rows x 128 codes. Segment-K-tile = K64 of one product (z1c1/z2c1/z1c2 x kc0..3).
// Per tile 2 phases (kk halves). Loads confirmed by per-wave vmcnt(4) FOLLOWED BY s_barrier
// (cross-wave landing guarantee) before any ds_read of that half. Counted vmcnt never 0 mid-loop.
__global__ __launch_bounds__(512, 2) void mfma_pass_kernel(
    const u16* __restrict__ z1, const u16* __restrict__ z2,
    const u16* __restrict__ c1, const u16* __restrict__ c2,
    const float* __restrict__ rowN,
    u32* __restrict__ g1k, u32* __restrict__ g2k)
{
    __shared__ __align__(16) u16 As[2 * 16384];   // [buf][kk half 8192] of short8 = 64 KB
    __shared__ __align__(16) u16 Bs[2 * 16384];   // 64 KB

    const int tid = threadIdx.x;
    const int lane = tid & 63;
    const int w = tid >> 6;
    const int wm = w >> 1, wn = w & 1;
    const int l15 = lane & 15, l4 = lane >> 4;

    // bijective XCD-pinned decode: slice s lives on XCDs {2s, 2s+1}
    const int wg = blockIdx.x;
    const int xcd = wg & 7;
    const int slice = xcd >> 1;
    const int rowtile = (xcd & 1) * 64 + (wg >> 3);
    const int row0 = rowtile * 256;
    const int code0 = slice * 2048;

    // per-thread staging bases (element units)
    const size_t a_base = (size_t)(row0 + (tid & 255)) * D_DIM + (tid >> 8) * 8;
    const size_t b_base = (size_t)(tid & 255) * D_DIM + (tid >> 8) * 8;

    // stage one kk-half of tile t into buffer dbuf: 2 A-loads + 2 B-loads per thread
    auto stage_half = [&](int t, int kk, int dbuf) {
        const int ct = t / 12, sub = t % 12;
        const int seg = sub >> 2, kc = sub & 3;
        const u16* Ap = (seg == 1) ? z2 : z1;
        const u16* Bp = (seg == 2) ? c2 : c1;
        const int koff = kc * 64 + kk * 32;
        const size_t cbe = (size_t)(code0 + ct * 256) * D_DIM;
        u16* ad = As + dbuf * 16384 + kk * 8192 + tid * 8;
        u16* bd = Bs + dbuf * 16384 + kk * 8192 + tid * 8;
        GL_LDS(Ap + a_base + koff,        ad);
        GL_LDS(Ap + a_base + koff + 16,   ad + 4096);
        GL_LDS(Bp + cbe + b_base + koff,      bd);
        GL_LDS(Bp + cbe + b_base + koff + 16, bd + 4096);
    };

    // row constants: rn bits for packed keys
    float rnv[16];
    u32 rnb[16];
    #pragma unroll
    for (int fm = 0; fm < 4; ++fm)
        #pragma unroll
        for (int r = 0; r < 4; ++r) {
            float rv = rowN[row0 + wm * 64 + fm * 16 + l4 * 4 + r];
            rnv[fm * 4 + r] = rv;
            rnb[fm * 4 + r] = __float_as_uint(rv) - 1024u;
        }

    u32 b1k[16], b2k[16];
    #pragma unroll
    for (int k = 0; k < 16; ++k) { b1k[k] = 0xFFFFFFFFu; b2k[k] = 0xFFFFFFFFu; }

    f32x4 acc[4][8];
    #pragma unroll
    for (int fm = 0; fm < 4; ++fm)
        #pragma unroll
        for (int fn = 0; fn < 8; ++fn) acc[fm][fn] = (f32x4){0.f, 0.f, 0.f, 0.f};

    // prologue: both halves of tile 0
    stage_half(0, 0, 0);
    stage_half(0, 1, 0);

    for (int t = 0; t < NTT; ++t) {
        const int buf = t & 1;
        #pragma unroll
        for (int kk = 0; kk < 2; ++kk) {
            // wait own loads for THIS half, then barrier => all waves' loads landed
            if (t == NTT - 1 && kk == 1) { asm volatile("s_waitcnt vmcnt(0)" ::: "memory"); }
            else                          { asm volatile("s_waitcnt vmcnt(4)" ::: "memory"); }
            __builtin_amdgcn_s_barrier();

            // issue next tile's matching half early (lands under this phase's MFMA + next)
            if (t + 1 < NTT) stage_half(t + 1, kk, buf ^ 1);

            const u16* Ab = As + buf * 16384 + kk * 8192;
            const u16* Bb = Bs + buf * 16384 + kk * 8192;
            short8 a[4], b[8];
            #pragma unroll
            for (int fm = 0; fm < 4; ++fm)
                a[fm] = *(const short8*)(Ab + (l4 * 256 + wm * 64 + fm * 16 + l15) * 8);
            #pragma unroll
            for (int fn = 0; fn < 8; ++fn)
                b[fn] = *(const short8*)(Bb + (l4 * 256 + wn * 128 + fn * 16 + l15) * 8);

            asm volatile("s_waitcnt lgkmcnt(0)" ::: "memory");
            __builtin_amdgcn_sched_barrier(0);
            __builtin_amdgcn_s_setprio(1);
            #pragma unroll
            for (int fm = 0; fm < 4; ++fm)
                #pragma unroll
                for (int fn = 0; fn < 8; ++fn)
                    acc[fm][fn] = __builtin_amdgcn_mfma_f32_16x16x32_bf16(a[fm], b[fn], acc[fm][fn], 0, 0, 0);
            __builtin_amdgcn_s_setprio(0);
            __builtin_amdgcn_s_barrier();
        }

        if (t % 12 == 11) {
            // per-code-tile epilogue: dist = fl(rn - 2*dot); packed-u32 top-2; reset acc
            const int cbase = code0 + (t / 12) * 256;
            #pragma unroll
            for (int fn = 0; fn < 8; ++fn) {
                u32 code = (u32)(cbase + wn * 128 + fn * 16 + l15);
                #pragma unroll
                for (int fm = 0; fm < 4; ++fm)
                    #pragma unroll
                    for (int r2 = 0; r2 < 4; ++r2) {
                        int k16 = fm * 4 + r2;
                        float dist = fmaf(-2.0f, acc[fm][fn][r2], rnv[k16]);
                        u32 key = ((__float_as_uint(dist) - rnb[k16]) << 13) + code;
                        u32 mx = b1k[k16] > key ? b1k[k16] : key;
                        b1k[k16] = b1k[k16] < key ? b1k[k16] : key;
                        b2k[k16] = b2k[k16] < mx ? b2k[k16] : mx;
                        acc[fm][fn][r2] = 0.f;
                    }
            }
        }
    }

    // 16-lane merge (same rows across l15); packed keys carry lex tie-break
    #pragma unroll
    for (int off = 1; off < 16; off <<= 1) {
        #pragma unroll
        for (int k = 0; k < 16; ++k) {
            u32 o1 = (u32)__shfl_xor((int)b1k[k], off);
            u32 o2 = (u32)__shfl_xor((int)b2k[k], off);
            u32 mx = b1k[k] > o1 ? b1k[k] : o1;
            b1k[k] = b1k[k] < o1 ? b1k[k] : o1;
            u32 mn2 = b2k[k] < o2 ? b2k[k] : o2;
            b2k[k] = mn2 < mx ? mn2 : mx;
        }
    }
    // cross-wave (wn) merge via reused LDS
    __syncthreads();
    u32* mk1 = (u32*)As;           // [2][256]
    u32* mk2 = mk1 + 512;
    if (l15 == 0) {
        #pragma unroll
        for (int fm = 0; fm < 4; ++fm)
            #pragma unroll
            for (int r2 = 0; r2 < 4; ++r2) {
                int rl = wm * 64 + fm * 16 + l4 * 4 + r2;
                mk1[wn * 256 + rl] = b1k[fm * 4 + r2];
                mk2[wn * 256 + rl] = b2k[fm * 4 + r2];
            }
    }
    __syncthreads();
    if (tid < 256) {
        u32 a1 = mk1[tid], b1 = mk1[256 + tid];
        u32 a2 = mk2[tid], b2 = mk2[256 + tid];
        u32 B1 = a1 < b1 ? a1 : b1;
        u32 mx = a1 > b1 ? a1 : b1;
        u32 mn2 = a2 < b2 ? a2 : b2;
        u32 B2 = mn2 < mx ? mn2 : mx;
        g1k[(size_t)slice * N_ROWS + row0 + tid] = B1;
        g2k[(size_t)slice * N_ROWS + row0 + tid] = B2;
    }
}

// ---------------- combine 4 slices, write idx, flag ambiguous rows ----------------
__global__ void combine_kernel(const u32* __restrict__ g1k, const u32* __restrict__ g2k,
                               int* __restrict__ idx_i, float* __restrict__ idx_f,
                               int* __restrict__ cand2, int* __restrict__ flag_list,
                               int* __restrict__ flag_count)
{
    int row = blockIdx.x * 256 + threadIdx.x;
    u32 B1 = 0xFFFFFFFFu, B2 = 0xFFFFFFFFu;
    #pragma unroll
    for (int s = 0; s < 4; ++s) {
        u32 o1 = g1k[(size_t)s * N_ROWS + row];
        u32 o2 = g2k[(size_t)s * N_ROWS + row];
        u32 mx = B1 > o1 ? B1 : o1;
        B1 = B1 < o1 ? B1 : o1;
        u32 mn2 = B2 < o2 ? B2 : o2;
        B2 = mn2 < mx ? mn2 : mx;
    }
    int i1 = (int)(B1 & 8191u);
    idx_i[row] = i1;
    idx_f[row] = (float)i1;
    cand2[row] = (int)(B2 & 8191u);
    if ((B2 >> 13) - (B1 >> 13) <= GUARD_STEPS) {
        int p = atomicAdd(flag_count, 1);
        flag_list[p] = row;
    }
}

// ---------------- lite rescan: one wave per flagged row, exact f32 dots of top-2 ----------------
__global__ __launch_bounds__(256) void lite_rescan_kernel(
    const float* __restrict__ z, const float* __restrict__ cb,
    const float* __restrict__ rowN, const int* __restrict__ flag_list,
    const int* __restrict__ flag_count, const int* __restrict__ cand2,
    int* __restrict__ idx_i, float* __restrict__ idx_f)
{
    int nflag = *flag_count;
    int widx = blockIdx.x * 4 + (threadIdx.x >> 6);
    if (widx >= nflag) return;
    int lane = threadIdx.x & 63;
    int row = flag_list[widx];
    int i1 = idx_i[row];
    int i2 = cand2[row];
    float rn = rowN[row];
    float4 zv = *(const float4*)(z + (size_t)row * D_DIM + lane * 4);
    float4 c1v = *(const float4*)(cb + (size_t)i1 * D_DIM + lane * 4);
    float4 c2v = *(const float4*)(cb + (size_t)i2 * D_DIM + lane * 4);
    float s1 = zv.x * c1v.x;
    s1 = fmaf(zv.y, c1v.y, s1);
    s1 = fmaf(zv.z, c1v.z, s1);
    s1 = fmaf(zv.w, c1v.w, s1);
    float s2 = zv.x * c2v.x;
    s2 = fmaf(zv.y, c2v.y, s2);
    s2 = fmaf(zv.z, c2v.z, s2);
    s2 = fmaf(zv.w, c2v.w, s2);
    #pragma unroll
    for (int off = 32; off; off >>= 1) {
        s1 += __shfl_xor(s1, off);
        s2 += __shfl_xor(s2, off);
    }
    float d1 = fmaf(-2.0f, s1, rn);
    float d2 = fmaf(-2.0f, s2, rn);
    bool w2 = (d2 < d1) || (d2 == d1 && i2 < i1);
    int win = w2 ? i2 : i1;
    if (lane == 0) {
        idx_i[row] = win;
        idx_f[row] = (float)win;
    }
}

// ---------------- z_q epilogue: one wave per row ----------------
__global__ void finalize_kernel(const float* __restrict__ z, const float* __restrict__ cb,
                                const float* __restrict__ noise, const int* __restrict__ idx,
                                float* __restrict__ zq)
{
    int gid = blockIdx.x * blockDim.x + threadIdx.x;
    int row = gid >> 6;
    int lane = gid & 63;
    if (row >= N_ROWS) return;
    const float4* zr = (const float4*)(z + (size_t)row * D_DIM);
    const float4* nr = (const float4*)(noise + (size_t)row * D_DIM);
    int k = idx[row];
    const float4* cr = (const float4*)(cb + (size_t)k * D_DIM);
    float4 zv = zr[lane], nv = nr[lane], cv = cr[lane];
    float4 dir, rv;
    dir.x = cv.x - zv.x; dir.y = cv.y - zv.y; dir.z = cv.z - zv.z; dir.w = cv.w - zv.w;
    rv.x = nv.x * 0.001f + dir.x; rv.y = nv.y * 0.001f + dir.y;
    rv.z = nv.z * 0.001f + dir.z; rv.w = nv.w * 0.001f + dir.w;
    float s_d = dir.x*dir.x + dir.y*dir.y + dir.z*dir.z + dir.w*dir.w;
    float s_r = rv.x*rv.x + rv.y*rv.y + rv.z*rv.z + rv.w*rv.w;
    #pragma unroll
    for (int off = 32; off; off >>= 1) {
        s_d += __shfl_xor(s_d, off);
        s_r += __shfl_xor(s_r, off);
    }
    float mag = sqrtf(s_d);
    float nrm = sqrtf(s_r);
    float scale = mag / fmaxf(nrm, 1e-12f);
    float4 o;
    o.x = zv.x + rv.x * scale; o.y = zv.y + rv.y * scale;
    o.z = zv.z + rv.z * scale; o.w = zv.w + rv.w * scale;
    ((float4*)(zq + (size_t)row * D_DIM))[lane] = o;
}

// ---------------- perplexity ----------------
__global__ void zero_kernel(int* __restrict__ h, int* __restrict__ cnt) {
    int i = blockIdx.x * 256 + threadIdx.x;
    if (i < K_CODES) h[i] = 0;
    if (i == K_CODES) *cnt = 0;
}
__global__ void hist_kernel(const int* __restrict__ idx, int* __restrict__ h) {
    int i = blockIdx.x * blockDim.x + threadIdx.x;
    if (i < N_ROWS) atomicAdd(&h[idx[i]], 1);
}
__global__ void perplexity_kernel(const int* __restrict__ h, float* __restrict__ out) {
    __shared__ double red[256];
    int tid = threadIdx.x;
    double s = 0.0;
    for (int j = tid; j < K_CODES; j += 256) {
        float p = (float)h[j] / 32768.0f;
        float t = p * logf(p + 1e-10f);
        s += (double)t;
    }
    red[tid] = s;
    __syncthreads();
    for (int off = 128; off; off >>= 1) {
        if (tid < off) red[tid] += red[tid + off];
        __syncthreads();
    }
    if (tid == 0) out[0] = (float)exp(-red[0]);
}

// ================= fallback f32 path (round-1, known-good) =================
#define BM 64
#define BN 128
#define BD 32
#define TM 4
#define TN 8
__global__ __launch_bounds__(256) void argmin_kernel(
    const float* __restrict__ z, const float* __restrict__ cb,
    const float* __restrict__ rowN, const float* __restrict__ codeN,
    int* __restrict__ idx_out, float* __restrict__ idx_f_out)
{
    __shared__ float As[BD][BM + 4];
    __shared__ float Bs[BD][BN + 4];
    const int tid = threadIdx.x;
    const int tx = tid & 15;
    const int ty = tid >> 4;
    const int row0 = blockIdx.x * BM;
    float rn[TM];
    #pragma unroll
    for (int tm = 0; tm < TM; ++tm) rn[tm] = rowN[row0 + ty * TM + tm];
    float bestVal[TM]; int bestIdx[TM];
    #pragma unroll
    for (int tm = 0; tm < TM; ++tm) { bestVal[tm] = INFINITY; bestIdx[tm] = 0; }
    for (int t0 = 0; t0 < K_CODES; t0 += BN) {
        float acc[TM][TN];
        #pragma unroll
        for (int tm = 0; tm < TM; ++tm)
            #pragma unroll
            for (int tn = 0; tn < TN; ++tn) acc[tm][tn] = 0.0f;
        for (int d0 = 0; d0 < D_DIM; d0 += BD) {
            __syncthreads();
            #pragma unroll
            for (int r = 0; r < 2; ++r) {
                int g = tid + 256 * r;
                int m = g >> 3, seg = g & 7;
                float4 v = *(const float4*)(z + (size_t)(row0 + m) * D_DIM + d0 + seg * 4);
                As[seg * 4 + 0][m] = v.x; As[seg * 4 + 1][m] = v.y;
                As[seg * 4 + 2][m] = v.z; As[seg * 4 + 3][m] = v.w;
            }
            #pragma unroll
            for (int r = 0; r < 4; ++r) {
                int g = tid + 256 * r;
                int c = g >> 3, seg = g & 7;
                float4 v = *(const float4*)(cb + (size_t)(t0 + c) * D_DIM + d0 + seg * 4);
                Bs[seg * 4 + 0][c] = v.x; Bs[seg * 4 + 1][c] = v.y;
                Bs[seg * 4 + 2][c] = v.z; Bs[seg * 4 + 3][c] = v.w;
            }
            __syncthreads();
            #pragma unroll
            for (int d = 0; d < BD; ++d) {
                float a[TM], b[TN];
                #pragma unroll
                for (int tm = 0; tm < TM; ++tm) a[tm] = As[d][ty * TM + tm];
                #pragma unroll
                for (int tn = 0; tn < TN; ++tn) b[tn] = Bs[d][tx * TN + tn];
                #pragma unroll
                for (int tm = 0; tm < TM; ++tm)
                    #pragma unroll
                    for (int tn = 0; tn < TN; ++tn)
                        acc[tm][tn] = fmaf(a[tm], b[tn], acc[tm][tn]);
            }
        }
        #pragma unroll
        for (int tn = 0; tn < TN; ++tn) {
            int code = t0 + tx * TN + tn;
            float cn = codeN[code];
            #pragma unroll
            for (int tm = 0; tm < TM; ++tm) {
                float c2 = 2.0f * acc[tm][tn];
                float ts = rn[tm] + cn;
                float dist = ts - c2;
                if (dist < bestVal[tm]) { bestVal[tm] = dist; bestIdx[tm] = code; }
            }
        }
    }
    #pragma unroll
    for (int off = 8; off; off >>= 1) {
        #pragma unroll
        for (int tm = 0; tm < TM; ++tm) {
            float ov = __shfl_xor(bestVal[tm], off, 16);
            int   oi = __shfl_xor(bestIdx[tm], off, 16);
            if (ov < bestVal[tm] || (ov == bestVal[tm] && oi < bestIdx[tm])) {
                bestVal[tm] = ov; bestIdx[tm] = oi;
            }
        }
    }
    if (tx == 0) {
        #pragma unroll
        for (int tm = 0; tm < TM; ++tm) {
            int row = row0 + ty * TM + tm;
            idx_out[row] = bestIdx[tm];
            idx_f_out[row] = (float)bestIdx[tm];
        }
    }
}

// =====================================================================
extern "C" void kernel_launch(void* const* d_in, const int* in_sizes, int n_in,
                              void* d_out, int out_size, void* d_ws, size_t ws_size,
                              hipStream_t stream)
{
    const float* z     = (const float*)d_in[0];
    const float* cb    = (const float*)d_in[1];
    const float* noise = (const float*)d_in[2];

    float* out   = (float*)d_out;
    float* zq    = out;
    float* idx_f = out + (size_t)N_ROWS * D_DIM;
    float* perp  = idx_f + N_ROWS;

    char* ws = (char*)d_ws;

    // workspace layout (bytes)
    const size_t OFF_Z1    = 0;
    const size_t OFF_Z2    = 16777216;
    const size_t OFF_C1    = 33554432;
    const size_t OFF_C2    = 37748736;
    const size_t OFF_ROWN  = 41943040;
    const size_t OFF_CODN  = 42074112;
    const size_t OFF_IDX   = 42106880;
    const size_t OFF_FLAGL = 42237952;
    const size_t OFF_FLAGC = 42369024;
    const size_t OFF_HIST  = 42369280;
    const size_t OFF_CAND2 = 42402048;
    const size_t OFF_G1K   = 42533120;
    const size_t OFF_G2K   = 43057408;
    const size_t NEED      = 43581696;

    if (ws_size >= NEED) {
        u16*   z1    = (u16*)(ws + OFF_Z1);
        u16*   z2    = (u16*)(ws + OFF_Z2);
        u16*   c1    = (u16*)(ws + OFF_C1);
        u16*   c2    = (u16*)(ws + OFF_C2);
        float* rowN  = (float*)(ws + OFF_ROWN);
        int*   idxi  = (int*)(ws + OFF_IDX);
        int*   flagl = (int*)(ws + OFF_FLAGL);
        int*   flagc = (int*)(ws + OFF_FLAGC);
        int*   hist  = (int*)(ws + OFF_HIST);
        int*   cand2 = (int*)(ws + OFF_CAND2);
        u32*   g1k   = (u32*)(ws + OFF_G1K);
        u32*   g2k   = (u32*)(ws + OFF_G2K);

        split_norm_kernel<<<N_ROWS / 4, 256, 0, stream>>>(z, z1, z2, rowN, N_ROWS);
        split_norm_kernel<<<K_CODES / 4, 256, 0, stream>>>(cb, c1, c2, (float*)(ws + OFF_CODN), K_CODES);
        zero_kernel<<<33, 256, 0, stream>>>(hist, flagc);
        mfma_pass_kernel<<<512, 512, 0, stream>>>(z1, z2, c1, c2, rowN, g1k, g2k);
        combine_kernel<<<N_ROWS / 256, 256, 0, stream>>>(g1k, g2k, idxi, idx_f, cand2,
                                                         flagl, flagc);
        lite_rescan_kernel<<<N_ROWS / 4, 256, 0, stream>>>(z, cb, rowN, flagl, flagc,
                                                           cand2, idxi, idx_f);
        hist_kernel<<<N_ROWS / 256, 256, 0, stream>>>(idxi, hist);
        finalize_kernel<<<(N_ROWS * 64) / 256, 256, 0, stream>>>(z, cb, noise, idxi, zq);
        perplexity_kernel<<<1, 256, 0, stream>>>(hist, perp);
    } else {
        // fallback: round-1 pure-f32 path
        int*   idxi  = (int*)ws;
        int*   hist  = (int*)(ws + (size_t)N_ROWS * 4);
        float* rowN  = (float*)(ws + (size_t)(N_ROWS + K_CODES) * 4);
        float* codeN = (float*)(ws + (size_t)(2 * N_ROWS + K_CODES) * 4);
        int*   fc    = (int*)(ws + (size_t)(2 * N_ROWS + 2 * K_CODES) * 4);

        row_norms_kernel<<<N_ROWS / 4, 256, 0, stream>>>(z, rowN, N_ROWS);
        row_norms_kernel<<<K_CODES / 4, 256, 0, stream>>>(cb, codeN, K_CODES);
        argmin_kernel<<<N_ROWS / BM, 256, 0, stream>>>(z, cb, rowN, codeN, idxi, idx_f);
        zero_kernel<<<33, 256, 0, stream>>>(hist, fc);
        hist_kernel<<<N_ROWS / 256, 256, 0, stream>>>(idxi, hist);
        finalize_kernel<<<(N_ROWS * 64) / 256, 256, 0, stream>>>(z, cb, noise, idxi, zq);
        perplexity_kernel<<<1, 256, 0, stream>>>(hist, perp);
    }
}

// Round 10
// 638.665 us; speedup vs baseline: 1.3220x; 1.2054x over previous
//
#include <hip/hip_runtime.h>
#include <math.h>

#define N_ROWS 32768
#define K_CODES 8192
#define D_DIM 256
#define GUARD_STEPS 4u
#define NCHUNK 256   // 32 code-tiles * 8 K32-chunks per block

typedef unsigned short u16;
typedef unsigned int u32;
typedef float f32x4 __attribute__((ext_vector_type(4)));
typedef short short8 __attribute__((ext_vector_type(8)));

#define GL_LDS(g, l) __builtin_amdgcn_global_load_lds( \
    (const __attribute__((address_space(1))) void*)(g), \
    (__attribute__((address_space(3))) void*)(l), 16, 0, 0)

// ---------------- bf16 split: x = hi + lo (both RNE bf16) ----------------
__device__ __forceinline__ void bf16_split(float x, u16& h, u16& l) {
    unsigned u = __float_as_uint(x);
    unsigned r = (u + 0x7fffu + ((u >> 16) & 1u)) >> 16;
    h = (u16)r;
    float hf = __uint_as_float(r << 16);
    float res = x - hf;               // exact (Sterbenz)
    unsigned u2 = __float_as_uint(res);
    unsigned r2 = (u2 + 0x7fffu + ((u2 >> 16) & 1u)) >> 16;
    l = (u16)r2;
}

// ---------------- fused split + row norm: one wave per row ----------------
__global__ void split_norm_kernel(const float* __restrict__ x, u16* __restrict__ hi,
                                  u16* __restrict__ lo, float* __restrict__ nrm, int nrows) {
    int gid = blockIdx.x * blockDim.x + threadIdx.x;
    int row = gid >> 6;
    int lane = gid & 63;
    if (row >= nrows) return;
    float4 v = ((const float4*)(x + (size_t)row * D_DIM))[lane];
    ushort4 h, l;
    bf16_split(v.x, h.x, l.x);
    bf16_split(v.y, h.y, l.y);
    bf16_split(v.z, h.z, l.z);
    bf16_split(v.w, h.w, l.w);
    ((ushort4*)(hi + (size_t)row * D_DIM))[lane] = h;
    ((ushort4*)(lo + (size_t)row * D_DIM))[lane] = l;
    double s = (double)v.x * v.x + (double)v.y * v.y + (double)v.z * v.z + (double)v.w * v.w;
    #pragma unroll
    for (int off = 32; off; off >>= 1) s += __shfl_xor(s, off);
    if (lane == 0) nrm[row] = (float)s;
}

// legacy norms (fallback path)
__global__ void row_norms_kernel(const float* __restrict__ x, float* __restrict__ nrm, int nrows) {
    int gid = blockIdx.x * blockDim.x + threadIdx.x;
    int row = gid >> 6;
    int lane = gid & 63;
    if (row >= nrows) return;
    float4 v = ((const float4*)(x + (size_t)row * D_DIM))[lane];
    double s = (double)v.x * v.x + (double)v.y * v.y + (double)v.z * v.z + (double)v.w * v.w;
    #pragma unroll
    for (int off = 32; off; off >>= 1) s += __shfl_xor(s, off);
    if (lane == 0) nrm[row] = (float)s;
}

// ---------------- pass A: z1-resident + double-buffered K32 stream, counted vmcnt ----------------
// 256 blocks (128-row tiles, 1/CU); 512 thr = 8 waves (wm 0..1 x wn 0..3); wave tile 64 rows x 64 codes.
// z1 [seg8 0..31][row 0..127] resident 64 KB (conflict-free layout, staged once).
// Per K32 chunk stage {z2 8K, c1 16K, c2 16K} dbuf; 5 loads/thread; vmcnt(5) never 0 mid-loop.
// Order per chunk: stage(c+1) -> vmcnt(5) -> barrier -> 16 ds_read -> lgkm0 -> 48 MFMA -> barrier.
__global__ __launch_bounds__(512, 2) void mfma_pass_kernel(
    const u16* __restrict__ z1, const u16* __restrict__ z2,
    const u16* __restrict__ c1, const u16* __restrict__ c2,
    const float* __restrict__ rowN,
    int* __restrict__ idx_i, float* __restrict__ idx_f, int* __restrict__ cand2,
    int* __restrict__ flag_list, int* __restrict__ flag_count)
{
    __shared__ __align__(16) u16 z1s[32 * 128 * 8];      // 64 KB resident
    __shared__ __align__(16) u16 z2s[2][4 * 128 * 8];    // 2 x 8 KB
    __shared__ __align__(16) u16 c1s[2][4 * 256 * 8];    // 2 x 16 KB
    __shared__ __align__(16) u16 c2s[2][4 * 256 * 8];    // 2 x 16 KB   -> 144 KB total

    const int tid = threadIdx.x;
    const int lane = tid & 63;
    const int w = tid >> 6;
    const int wm = w >> 2, wn = w & 3;
    const int l15 = lane & 15, l4 = lane >> 4;
    const int row0 = blockIdx.x * 128;

    // prologue: stage resident z1 [seg8][row] (linear dest, strided per-lane source)
    #pragma unroll
    for (int r = 0; r < 8; ++r) {
        int s = tid + 512 * r;
        int seg = s >> 7, rw = s & 127;
        GL_LDS(z1 + (size_t)(row0 + rw) * D_DIM + seg * 8, z1s + s * 8);
    }

    // stage one K32 chunk: 1 z2 + 2 c1 + 2 c2 loads per thread
    auto stage_chunk = [&](int c, int buf) {
        const int ct = c >> 3, kc = c & 7;
        const int cb = ct * 256, ko = kc * 32;
        {
            int seg = tid >> 7, rw = tid & 127;
            GL_LDS(z2 + (size_t)(row0 + rw) * D_DIM + ko + seg * 8, z2s[buf] + tid * 8);
        }
        #pragma unroll
        for (int r = 0; r < 2; ++r) {
            int s = tid + 512 * r;
            int seg = s >> 8, cr = s & 255;
            GL_LDS(c1 + (size_t)(cb + cr) * D_DIM + ko + seg * 8, c1s[buf] + s * 8);
        }
        #pragma unroll
        for (int r = 0; r < 2; ++r) {
            int s = tid + 512 * r;
            int seg = s >> 8, cr = s & 255;
            GL_LDS(c2 + (size_t)(cb + cr) * D_DIM + ko + seg * 8, c2s[buf] + s * 8);
        }
    };

    // row constants: rn (f32) + packed-key base bits
    float rnv[16];
    u32 rnb[16];
    #pragma unroll
    for (int fm = 0; fm < 4; ++fm)
        #pragma unroll
        for (int r = 0; r < 4; ++r) {
            float rv = rowN[row0 + wm * 64 + fm * 16 + l4 * 4 + r];
            rnv[fm * 4 + r] = rv;
            rnb[fm * 4 + r] = __float_as_uint(rv) - 1024u;
        }

    u32 b1k[16], b2k[16];
    #pragma unroll
    for (int k = 0; k < 16; ++k) { b1k[k] = 0xFFFFFFFFu; b2k[k] = 0xFFFFFFFFu; }

    f32x4 acc[4][4];
    #pragma unroll
    for (int fm = 0; fm < 4; ++fm)
        #pragma unroll
        for (int fn = 0; fn < 4; ++fn) acc[fm][fn] = (f32x4){0.f, 0.f, 0.f, 0.f};

    stage_chunk(0, 0);

    for (int c = 0; c < NCHUNK; ++c) {
        const int buf = c & 1;
        const int kc = c & 7;

        // issue next chunk early (buf^1 was last read in chunk c-1, sealed by its barrier)
        if (c + 1 < NCHUNK) {
            stage_chunk(c + 1, buf ^ 1);
            asm volatile("s_waitcnt vmcnt(5)" ::: "memory");   // chunk c landed (own loads)
        } else {
            asm volatile("s_waitcnt vmcnt(0)" ::: "memory");
        }
        __builtin_amdgcn_s_barrier();   // all waves' chunk-c loads landed

        short8 a1[4], a2[4], b1f[4], b2f[4];
        #pragma unroll
        for (int fm = 0; fm < 4; ++fm) {
            int rw = wm * 64 + fm * 16 + l15;
            a1[fm] = *(const short8*)(z1s + ((kc * 4 + l4) * 128 + rw) * 8);
            a2[fm] = *(const short8*)(z2s[buf] + (l4 * 128 + rw) * 8);
        }
        #pragma unroll
        for (int fn = 0; fn < 4; ++fn) {
            int cr = wn * 64 + fn * 16 + l15;
            b1f[fn] = *(const short8*)(c1s[buf] + (l4 * 256 + cr) * 8);
            b2f[fn] = *(const short8*)(c2s[buf] + (l4 * 256 + cr) * 8);
        }

        asm volatile("s_waitcnt lgkmcnt(0)" ::: "memory");
        __builtin_amdgcn_sched_barrier(0);
        __builtin_amdgcn_s_setprio(1);
        #pragma unroll
        for (int fm = 0; fm < 4; ++fm)
            #pragma unroll
            for (int fn = 0; fn < 4; ++fn) {
                acc[fm][fn] = __builtin_amdgcn_mfma_f32_16x16x32_bf16(a1[fm], b1f[fn], acc[fm][fn], 0, 0, 0);
                acc[fm][fn] = __builtin_amdgcn_mfma_f32_16x16x32_bf16(a2[fm], b1f[fn], acc[fm][fn], 0, 0, 0);
                acc[fm][fn] = __builtin_amdgcn_mfma_f32_16x16x32_bf16(a1[fm], b2f[fn], acc[fm][fn], 0, 0, 0);
            }
        __builtin_amdgcn_s_setprio(0);
        __builtin_amdgcn_s_barrier();

        if (kc == 7) {
            // per-code-tile epilogue: dist = fl(rn - 2*dot); packed-u32 top-2; reset acc
            const int cbase = (c >> 3) * 256;
            #pragma unroll
            for (int fn = 0; fn < 4; ++fn) {
                u32 code = (u32)(cbase + wn * 64 + fn * 16 + l15);
                #pragma unroll
                for (int fm = 0; fm < 4; ++fm)
                    #pragma unroll
                    for (int r2 = 0; r2 < 4; ++r2) {
                        int k16 = fm * 4 + r2;
                        float dist = fmaf(-2.0f, acc[fm][fn][r2], rnv[k16]);
                        u32 key = ((__float_as_uint(dist) - rnb[k16]) << 13) + code;
                        u32 mx = b1k[k16] > key ? b1k[k16] : key;
                        b1k[k16] = b1k[k16] < key ? b1k[k16] : key;
                        b2k[k16] = b2k[k16] < mx ? b2k[k16] : mx;
                        acc[fm][fn][r2] = 0.f;
                    }
            }
        }
    }

    // 16-lane merge (same rows across l15); packed keys carry lex tie-break
    #pragma unroll
    for (int off = 1; off < 16; off <<= 1) {
        #pragma unroll
        for (int k = 0; k < 16; ++k) {
            u32 o1 = (u32)__shfl_xor((int)b1k[k], off);
            u32 o2 = (u32)__shfl_xor((int)b2k[k], off);
            u32 mx = b1k[k] > o1 ? b1k[k] : o1;
            b1k[k] = b1k[k] < o1 ? b1k[k] : o1;
            u32 mn2 = b2k[k] < o2 ? b2k[k] : o2;
            b2k[k] = mn2 < mx ? mn2 : mx;
        }
    }
    // cross-wave (wn) merge via reused LDS (z2s buffers, after final barrier)
    __syncthreads();
    u32* mk1 = (u32*)&z2s[0][0];   // [4][128]
    u32* mk2 = mk1 + 512;
    if (l15 == 0) {
        #pragma unroll
        for (int fm = 0; fm < 4; ++fm)
            #pragma unroll
            for (int r2 = 0; r2 < 4; ++r2) {
                int rl = wm * 64 + fm * 16 + l4 * 4 + r2;
                mk1[wn * 128 + rl] = b1k[fm * 4 + r2];
                mk2[wn * 128 + rl] = b2k[fm * 4 + r2];
            }
    }
    __syncthreads();
    if (tid < 128) {
        u32 B1 = 0xFFFFFFFFu, B2 = 0xFFFFFFFFu;
        #pragma unroll
        for (int s = 0; s < 4; ++s) {
            u32 o1 = mk1[s * 128 + tid];
            u32 o2 = mk2[s * 128 + tid];
            u32 mx = B1 > o1 ? B1 : o1;
            B1 = B1 < o1 ? B1 : o1;
            u32 mn2 = B2 < o2 ? B2 : o2;
            B2 = mn2 < mx ? mn2 : mx;
        }
        int row = row0 + tid;
        int i1 = (int)(B1 & 8191u);
        idx_i[row] = i1;
        idx_f[row] = (float)i1;
        cand2[row] = (int)(B2 & 8191u);
        if ((B2 >> 13) - (B1 >> 13) <= GUARD_STEPS) {
            int p = atomicAdd(flag_count, 1);
            flag_list[p] = row;
        }
    }
}

// ---------------- lite rescan: one wave per flagged row, exact f32 dots of top-2 ----------------
__global__ __launch_bounds__(256) void lite_rescan_kernel(
    const float* __restrict__ z, const float* __restrict__ cb,
    const float* __restrict__ rowN, const int* __restrict__ flag_list,
    const int* __restrict__ flag_count, const int* __restrict__ cand2,
    int* __restrict__ idx_i, float* __restrict__ idx_f)
{
    int nflag = *flag_count;
    int widx = blockIdx.x * 4 + (threadIdx.x >> 6);
    if (widx >= nflag) return;
    int lane = threadIdx.x & 63;
    int row = flag_list[widx];
    int i1 = idx_i[row];
    int i2 = cand2[row];
    float rn = rowN[row];
    float4 zv = *(const float4*)(z + (size_t)row * D_DIM + lane * 4);
    float4 c1v = *(const float4*)(cb + (size_t)i1 * D_DIM + lane * 4);
    float4 c2v = *(const float4*)(cb + (size_t)i2 * D_DIM + lane * 4);
    float s1 = zv.x * c1v.x;
    s1 = fmaf(zv.y, c1v.y, s1);
    s1 = fmaf(zv.z, c1v.z, s1);
    s1 = fmaf(zv.w, c1v.w, s1);
    float s2 = zv.x * c2v.x;
    s2 = fmaf(zv.y, c2v.y, s2);
    s2 = fmaf(zv.z, c2v.z, s2);
    s2 = fmaf(zv.w, c2v.w, s2);
    #pragma unroll
    for (int off = 32; off; off >>= 1) {
        s1 += __shfl_xor(s1, off);
        s2 += __shfl_xor(s2, off);
    }
    float d1 = fmaf(-2.0f, s1, rn);
    float d2 = fmaf(-2.0f, s2, rn);
    bool w2 = (d2 < d1) || (d2 == d1 && i2 < i1);
    int win = w2 ? i2 : i1;
    if (lane == 0) {
        idx_i[row] = win;
        idx_f[row] = (float)win;
    }
}

// ---------------- z_q epilogue: one wave per row ----------------
__global__ void finalize_kernel(const float* __restrict__ z, const float* __restrict__ cb,
                                const float* __restrict__ noise, const int* __restrict__ idx,
                                float* __restrict__ zq)
{
    int gid = blockIdx.x * blockDim.x + threadIdx.x;
    int row = gid >> 6;
    int lane = gid & 63;
    if (row >= N_ROWS) return;
    const float4* zr = (const float4*)(z + (size_t)row * D_DIM);
    const float4* nr = (const float4*)(noise + (size_t)row * D_DIM);
    int k = idx[row];
    const float4* cr = (const float4*)(cb + (size_t)k * D_DIM);
    float4 zv = zr[lane], nv = nr[lane], cv = cr[lane];
    float4 dir, rv;
    dir.x = cv.x - zv.x; dir.y = cv.y - zv.y; dir.z = cv.z - zv.z; dir.w = cv.w - zv.w;
    rv.x = nv.x * 0.001f + dir.x; rv.y = nv.y * 0.001f + dir.y;
    rv.z = nv.z * 0.001f + dir.z; rv.w = nv.w * 0.001f + dir.w;
    float s_d = dir.x*dir.x + dir.y*dir.y + dir.z*dir.z + dir.w*dir.w;
    float s_r = rv.x*rv.x + rv.y*rv.y + rv.z*rv.z + rv.w*rv.w;
    #pragma unroll
    for (int off = 32; off; off >>= 1) {
        s_d += __shfl_xor(s_d, off);
        s_r += __shfl_xor(s_r, off);
    }
    float mag = sqrtf(s_d);
    float nrm = sqrtf(s_r);
    float scale = mag / fmaxf(nrm, 1e-12f);
    float4 o;
    o.x = zv.x + rv.x * scale; o.y = zv.y + rv.y * scale;
    o.z = zv.z + rv.z * scale; o.w = zv.w + rv.w * scale;
    ((float4*)(zq + (size_t)row * D_DIM))[lane] = o;
}

// ---------------- perplexity ----------------
__global__ void zero_kernel(int* __restrict__ h, int* __restrict__ cnt) {
    int i = blockIdx.x * 256 + threadIdx.x;
    if (i < K_CODES) h[i] = 0;
    if (i == K_CODES) *cnt = 0;
}
__global__ void hist_kernel(const int* __restrict__ idx, int* __restrict__ h) {
    int i = blockIdx.x * blockDim.x + threadIdx.x;
    if (i < N_ROWS) atomicAdd(&h[idx[i]], 1);
}
__global__ void perplexity_kernel(const int* __restrict__ h, float* __restrict__ out) {
    __shared__ double red[256];
    int tid = threadIdx.x;
    double s = 0.0;
    for (int j = tid; j < K_CODES; j += 256) {
        float p = (float)h[j] / 32768.0f;
        float t = p * logf(p + 1e-10f);
        s += (double)t;
    }
    red[tid] = s;
    __syncthreads();
    for (int off = 128; off; off >>= 1) {
        if (tid < off) red[tid] += red[tid + off];
        __syncthreads();
    }
    if (tid == 0) out[0] = (float)exp(-red[0]);
}

// ================= fallback f32 path (round-1, known-good) =================
#define BM 64
#define BN 128
#define BD 32
#define TM 4
#define TN 8
__global__ __launch_bounds__(256) void argmin_kernel(
    const float* __restrict__ z, const float* __restrict__ cb,
    const float* __restrict__ rowN, const float* __restrict__ codeN,
    int* __restrict__ idx_out, float* __restrict__ idx_f_out)
{
    __shared__ float As[BD][BM + 4];
    __shared__ float Bs[BD][BN + 4];
    const int tid = threadIdx.x;
    const int tx = tid & 15;
    const int ty = tid >> 4;
    const int row0 = blockIdx.x * BM;
    float rn[TM];
    #pragma unroll
    for (int tm = 0; tm < TM; ++tm) rn[tm] = rowN[row0 + ty * TM + tm];
    float bestVal[TM]; int bestIdx[TM];
    #pragma unroll
    for (int tm = 0; tm < TM; ++tm) { bestVal[tm] = INFINITY; bestIdx[tm] = 0; }
    for (int t0 = 0; t0 < K_CODES; t0 += BN) {
        float acc[TM][TN];
        #pragma unroll
        for (int tm = 0; tm < TM; ++tm)
            #pragma unroll
            for (int tn = 0; tn < TN; ++tn) acc[tm][tn] = 0.0f;
        for (int d0 = 0; d0 < D_DIM; d0 += BD) {
            __syncthreads();
            #pragma unroll
            for (int r = 0; r < 2; ++r) {
                int g = tid + 256 * r;
                int m = g >> 3, seg = g & 7;
                float4 v = *(const float4*)(z + (size_t)(row0 + m) * D_DIM + d0 + seg * 4);
                As[seg * 4 + 0][m] = v.x; As[seg * 4 + 1][m] = v.y;
                As[seg * 4 + 2][m] = v.z; As[seg * 4 + 3][m] = v.w;
            }
            #pragma unroll
            for (int r = 0; r < 4; ++r) {
                int g = tid + 256 * r;
                int c = g >> 3, seg = g & 7;
                float4 v = *(const float4*)(cb + (size_t)(t0 + c) * D_DIM + d0 + seg * 4);
                Bs[seg * 4 + 0][c] = v.x; Bs[seg * 4 + 1][c] = v.y;
                Bs[seg * 4 + 2][c] = v.z; Bs[seg * 4 + 3][c] = v.w;
            }
            __syncthreads();
            #pragma unroll
            for (int d = 0; d < BD; ++d) {
                float a[TM], b[TN];
                #pragma unroll
                for (int tm = 0; tm < TM; ++tm) a[tm] = As[d][ty * TM + tm];
                #pragma unroll
                for (int tn = 0; tn < TN; ++tn) b[tn] = Bs[d][tx * TN + tn];
                #pragma unroll
                for (int tm = 0; tm < TM; ++tm)
                    #pragma unroll
                    for (int tn = 0; tn < TN; ++tn)
                        acc[tm][tn] = fmaf(a[tm], b[tn], acc[tm][tn]);
            }
        }
        #pragma unroll
        for (int tn = 0; tn < TN; ++tn) {
            int code = t0 + tx * TN + tn;
            float cn = codeN[code];
            #pragma unroll
            for (int tm = 0; tm < TM; ++tm) {
                float c2 = 2.0f * acc[tm][tn];
                float ts = rn[tm] + cn;
                float dist = ts - c2;
                if (dist < bestVal[tm]) { bestVal[tm] = dist; bestIdx[tm] = code; }
            }
        }
    }
    #pragma unroll
    for (int off = 8; off; off >>= 1) {
        #pragma unroll
        for (int tm = 0; tm < TM; ++tm) {
            float ov = __shfl_xor(bestVal[tm], off, 16);
            int   oi = __shfl_xor(bestIdx[tm], off, 16);
            if (ov < bestVal[tm] || (ov == bestVal[tm] && oi < bestIdx[tm])) {
                bestVal[tm] = ov; bestIdx[tm] = oi;
            }
        }
    }
    if (tx == 0) {
        #pragma unroll
        for (int tm = 0; tm < TM; ++tm) {
            int row = row0 + ty * TM + tm;
            idx_out[row] = bestIdx[tm];
            idx_f_out[row] = (float)bestIdx[tm];
        }
    }
}

// =====================================================================
extern "C" void kernel_launch(void* const* d_in, const int* in_sizes, int n_in,
                              void* d_out, int out_size, void* d_ws, size_t ws_size,
                              hipStream_t stream)
{
    const float* z     = (const float*)d_in[0];
    const float* cb    = (const float*)d_in[1];
    const float* noise = (const float*)d_in[2];

    float* out   = (float*)d_out;
    float* zq    = out;
    float* idx_f = out + (size_t)N_ROWS * D_DIM;
    float* perp  = idx_f + N_ROWS;

    char* ws = (char*)d_ws;

    // workspace layout (bytes)
    const size_t OFF_Z1    = 0;
    const size_t OFF_Z2    = 16777216;
    const size_t OFF_C1    = 33554432;
    const size_t OFF_C2    = 37748736;
    const size_t OFF_ROWN  = 41943040;
    const size_t OFF_CODN  = 42074112;
    const size_t OFF_IDX   = 42106880;
    const size_t OFF_FLAGL = 42237952;
    const size_t OFF_FLAGC = 42369024;
    const size_t OFF_HIST  = 42369280;
    const size_t OFF_CAND2 = 42402048;
    const size_t NEED      = 42533120;

    if (ws_size >= NEED) {
        u16*   z1    = (u16*)(ws + OFF_Z1);
        u16*   z2    = (u16*)(ws + OFF_Z2);
        u16*   c1    = (u16*)(ws + OFF_C1);
        u16*   c2    = (u16*)(ws + OFF_C2);
        float* rowN  = (float*)(ws + OFF_ROWN);
        int*   idxi  = (int*)(ws + OFF_IDX);
        int*   flagl = (int*)(ws + OFF_FLAGL);
        int*   flagc = (int*)(ws + OFF_FLAGC);
        int*   hist  = (int*)(ws + OFF_HIST);
        int*   cand2 = (int*)(ws + OFF_CAND2);

        split_norm_kernel<<<N_ROWS / 4, 256, 0, stream>>>(z, z1, z2, rowN, N_ROWS);
        split_norm_kernel<<<K_CODES / 4, 256, 0, stream>>>(cb, c1, c2, (float*)(ws + OFF_CODN), K_CODES);
        zero_kernel<<<33, 256, 0, stream>>>(hist, flagc);
        mfma_pass_kernel<<<N_ROWS / 128, 512, 0, stream>>>(z1, z2, c1, c2, rowN,
                                                           idxi, idx_f, cand2, flagl, flagc);
        lite_rescan_kernel<<<N_ROWS / 4, 256, 0, stream>>>(z, cb, rowN, flagl, flagc,
                                                           cand2, idxi, idx_f);
        hist_kernel<<<N_ROWS / 256, 256, 0, stream>>>(idxi, hist);
        finalize_kernel<<<(N_ROWS * 64) / 256, 256, 0, stream>>>(z, cb, noise, idxi, zq);
        perplexity_kernel<<<1, 256, 0, stream>>>(hist, perp);
    } else {
        // fallback: round-1 pure-f32 path
        int*   idxi  = (int*)ws;
        int*   hist  = (int*)(ws + (size_t)N_ROWS * 4);
        float* rowN  = (float*)(ws + (size_t)(N_ROWS + K_CODES) * 4);
        float* codeN = (float*)(ws + (size_t)(2 * N_ROWS + K_CODES) * 4);
        int*   fc    = (int*)(ws + (size_t)(2 * N_ROWS + 2 * K_CODES) * 4);

        row_norms_kernel<<<N_ROWS / 4, 256, 0, stream>>>(z, rowN, N_ROWS);
        row_norms_kernel<<<K_CODES / 4, 256, 0, stream>>>(cb, codeN, K_CODES);
        argmin_kernel<<<N_ROWS / BM, 256, 0, stream>>>(z, cb, rowN, codeN, idxi, idx_f);
        zero_kernel<<<33, 256, 0, stream>>>(hist, fc);
        hist_kernel<<<N_ROWS / 256, 256, 0, stream>>>(idxi, hist);
        finalize_kernel<<<(N_ROWS * 64) / 256, 256, 0, stream>>>(z, cb, noise, idxi, zq);
        perplexity_kernel<<<1, 256, 0, stream>>>(hist, perp);
    }
}